// Round 1
// baseline (214.705 us; speedup 1.0000x reference)
//
#include <hip/hip_runtime.h>
#include <cstdint>
#include <cstddef>

typedef __bf16 bf16x8 __attribute__((ext_vector_type(8)));
typedef float f32x4 __attribute__((ext_vector_type(4)));

#define L_SEQ 32768
#define H_DIM 512
#define P_DIM 256
#define NP2   512      // 2P = K and N of both GEMMs
#define CHUNK 32
#define NCHUNK 1024    // L / CHUNK

__device__ __forceinline__ void gload_lds16(const void* g, void* l) {
    __builtin_amdgcn_global_load_lds(
        (const __attribute__((address_space(1))) void*)g,
        (__attribute__((address_space(3))) void*)l,
        16, 0, 0);
}

// ---------------- per-channel parameter precompute ----------------
// par layout (floats): [0]=Ar [256]=Ai [512]=coefR [768]=coefI [1024]=PowR [1280]=PowI
__global__ void prep_kernel(const float* __restrict__ Lre, const float* __restrict__ Lim,
                            const float* __restrict__ lstep, float* __restrict__ par) {
    int p = threadIdx.x;
    if (p >= P_DIM) return;
    float lr = fminf(Lre[p], -1e-4f);       // clip_eigs
    float li = Lim[p];
    float st = expf(lstep[p]);
    float er = expf(lr * st);
    float ph = li * st;
    float ar = er * cosf(ph);
    float ai = er * sinf(ph);
    // coeff = (Lambda_bar - 1) / Lambda
    float den = lr * lr + li * li;
    float mr = ar - 1.0f, mi = ai;
    float cr = (mr * lr + mi * li) / den;
    float ci = (mi * lr - mr * li) / den;
    // Lambda_bar^CHUNK = exp(CHUNK * Lambda * step)
    float e32  = expf((float)CHUNK * lr * st);
    float ph32 = (float)CHUNK * ph;
    float pr = e32 * cosf(ph32);
    float pi = e32 * sinf(ph32);
    par[p] = ar;        par[256 + p] = ai;
    par[512 + p] = cr;  par[768 + p] = ci;
    par[1024 + p] = pr; par[1280 + p] = pi;
}

// Bt[n][k]: n in [0,512) (re rows 0..255, im rows 256..511), k = h in [0,512)
__global__ void build_B_kernel(const float* __restrict__ Bre, const float* __restrict__ Bim,
                               const float* __restrict__ par, __bf16* __restrict__ Bt) {
    int idx = blockIdx.x * blockDim.x + threadIdx.x;   // [0, P*H)
    int p = idx >> 9;
    int h = idx & 511;
    float cr = par[512 + p], ci = par[768 + p];
    float br = Bre[idx], bi = Bim[idx];
    Bt[(size_t)p * NP2 + h]         = (__bf16)(cr * br - ci * bi);
    Bt[(size_t)(256 + p) * NP2 + h] = (__bf16)(cr * bi + ci * br);
}

// Ct[h][q]: q<256 -> 2*C_re[h][q], q>=256 -> -2*C_im[h][q-256]
__global__ void build_C_kernel(const float* __restrict__ Cre, const float* __restrict__ Cim,
                               __bf16* __restrict__ Ct) {
    int idx = blockIdx.x * blockDim.x + threadIdx.x;   // [0, H*P)
    int h = idx >> 8;
    int q = idx & 255;
    Ct[(size_t)h * NP2 + q]       = (__bf16)( 2.0f * Cre[idx]);
    Ct[(size_t)h * NP2 + 256 + q] = (__bf16)(-2.0f * Cim[idx]);
}

__global__ void cast_u_kernel(const float4* __restrict__ in, bf16x8* __restrict__ out, int n8) {
    int i = blockIdx.x * blockDim.x + threadIdx.x;
    if (i >= n8) return;
    float4 a = in[2 * i], b = in[2 * i + 1];
    bf16x8 v;
    v[0] = (__bf16)a.x; v[1] = (__bf16)a.y; v[2] = (__bf16)a.z; v[3] = (__bf16)a.w;
    v[4] = (__bf16)b.x; v[5] = (__bf16)b.y; v[6] = (__bf16)b.z; v[7] = (__bf16)b.w;
    out[i] = v;
}

// ---------------- GEMM: A(M,512) bf16 row-major  x  Bt(512,512) bf16 (N,K) ----------------
// 128x128 tile, BK=64, 4 waves each computing 64x64 (4x4 frags of 16x16x32 MFMA).
template<bool FUSE>
__global__ __launch_bounds__(256)
void gemm_bt_kernel(const __bf16* __restrict__ A, const __bf16* __restrict__ Bt,
                    float* __restrict__ Cout, const float* __restrict__ Dvec,
                    const float* __restrict__ U) {
    const int K = NP2, N = NP2;
    __shared__ __bf16 As[128 * 64];
    __shared__ __bf16 Bs[128 * 64];
    const int t = threadIdx.x;
    const int l = t & 63;
    const int w = t >> 6;
    const int wr = w >> 1, wc = w & 1;
    const int row0 = blockIdx.x * 128;
    const int col0 = blockIdx.y * 128;
    const int lr = l & 15;
    const int lk = (l >> 4) * 8;
    f32x4 acc[4][4] = {};

    for (int k0 = 0; k0 < K; k0 += 64) {
#pragma unroll
        for (int i = 0; i < 4; ++i) {
            int off = i * 256 + t;        // 16B-chunk id in tile, [0,1024)
            int r  = off >> 3;            // row in tile [0,128)
            int ce = (off & 7) * 8;       // bf16 col within row
            gload_lds16(A  + (size_t)(row0 + r) * K + (k0 + ce), As + off * 8);
            gload_lds16(Bt + (size_t)(col0 + r) * K + (k0 + ce), Bs + off * 8);
        }
        asm volatile("s_waitcnt vmcnt(0)" ::: "memory");
        __syncthreads();
#pragma unroll
        for (int kk = 0; kk < 64; kk += 32) {
            bf16x8 a[4], b[4];
#pragma unroll
            for (int m = 0; m < 4; ++m)
                a[m] = *reinterpret_cast<const bf16x8*>(As + (wr * 64 + m * 16 + lr) * 64 + kk + lk);
#pragma unroll
            for (int n = 0; n < 4; ++n)
                b[n] = *reinterpret_cast<const bf16x8*>(Bs + (wc * 64 + n * 16 + lr) * 64 + kk + lk);
#pragma unroll
            for (int m = 0; m < 4; ++m)
#pragma unroll
                for (int n = 0; n < 4; ++n)
                    acc[m][n] = __builtin_amdgcn_mfma_f32_16x16x32_bf16(a[m], b[n], acc[m][n], 0, 0, 0);
        }
        __syncthreads();
    }

    const int lg = (l >> 4) * 4;
#pragma unroll
    for (int m = 0; m < 4; ++m) {
#pragma unroll
        for (int n = 0; n < 4; ++n) {
            int col = col0 + wc * 64 + n * 16 + lr;
#pragma unroll
            for (int j = 0; j < 4; ++j) {
                int row = row0 + wr * 64 + m * 16 + lg + j;
                size_t o = (size_t)row * N + col;
                float v = acc[m][n][j];
                if (FUSE) v += Dvec[col] * U[o];
                Cout[o] = v;
            }
        }
    }
}

// ---------------- chunked scan ----------------
__global__ void scanA_kernel(const float* __restrict__ Bu, const float* __restrict__ par,
                             float* __restrict__ Fr, float* __restrict__ Fi) {
    int g = blockIdx.x;
    int p = threadIdx.x;
    float ar = par[p], ai = par[256 + p];
    const float* bu = Bu + (size_t)g * CHUNK * NP2;
    float xr = 0.f, xi = 0.f;
#pragma unroll 4
    for (int i = 0; i < CHUNK; ++i) {
        float br = bu[i * NP2 + p];
        float bi = bu[i * NP2 + 256 + p];
        float nr = fmaf(ar, xr, fmaf(-ai, xi, br));
        float ni = fmaf(ar, xi, fmaf( ai, xr, bi));
        xr = nr; xi = ni;
    }
    Fr[g * 256 + p] = xr;
    Fi[g * 256 + p] = xi;
}

__global__ void scanB_kernel(const float* __restrict__ Fr, const float* __restrict__ Fi,
                             const float* __restrict__ par,
                             float* __restrict__ Cr, float* __restrict__ Ci) {
    int p = threadIdx.x;
    float pr = par[1024 + p], pi = par[1280 + p];
    float er = 0.f, ei = 0.f;
    for (int g = 0; g < NCHUNK; ++g) {
        Cr[g * 256 + p] = er;
        Ci[g * 256 + p] = ei;
        float fr = Fr[g * 256 + p], fi = Fi[g * 256 + p];
        float nr = fmaf(pr, er, fmaf(-pi, ei, fr));
        float ni = fmaf(pr, ei, fmaf( pi, er, fi));
        er = nr; ei = ni;
    }
}

__global__ void scanC_kernel(const float* __restrict__ Bu, const float* __restrict__ par,
                             const float* __restrict__ Cr, const float* __restrict__ Ci,
                             __bf16* __restrict__ xs) {
    int g = blockIdx.x;
    int p = threadIdx.x;
    float ar = par[p], ai = par[256 + p];
    float xr = Cr[g * 256 + p], xi = Ci[g * 256 + p];
    const float* bu = Bu + (size_t)g * CHUNK * NP2;
    __bf16* xo = xs + (size_t)g * CHUNK * NP2;
#pragma unroll 4
    for (int i = 0; i < CHUNK; ++i) {
        float br = bu[i * NP2 + p];
        float bi = bu[i * NP2 + 256 + p];
        float nr = fmaf(ar, xr, fmaf(-ai, xi, br));
        float ni = fmaf(ar, xi, fmaf( ai, xr, bi));
        xr = nr; xi = ni;
        xo[i * NP2 + p]       = (__bf16)xr;
        xo[i * NP2 + 256 + p] = (__bf16)xi;
    }
}

extern "C" void kernel_launch(void* const* d_in, const int* in_sizes, int n_in,
                              void* d_out, int out_size, void* d_ws, size_t ws_size,
                              hipStream_t stream) {
    const float* u   = (const float*)d_in[0];
    const float* Lre = (const float*)d_in[1];
    const float* Lim = (const float*)d_in[2];
    const float* Bre = (const float*)d_in[3];
    const float* Bim = (const float*)d_in[4];
    const float* Cre = (const float*)d_in[5];
    const float* Cim = (const float*)d_in[6];
    const float* Dv  = (const float*)d_in[7];
    const float* lst = (const float*)d_in[8];

    char* w = (char*)d_ws;
    size_t off = 0;
    float* par = (float*)(w + off);      off += 16 * 1024;
    __bf16* Btm = (__bf16*)(w + off);    off += (size_t)NP2 * NP2 * 2;      // 512 KB
    __bf16* Ctm = (__bf16*)(w + off);    off += (size_t)NP2 * NP2 * 2;      // 512 KB
    float* Fr  = (float*)(w + off);      off += (size_t)NCHUNK * 256 * 4;   // 1 MB
    float* Fi  = (float*)(w + off);      off += (size_t)NCHUNK * 256 * 4;
    float* Car = (float*)(w + off);      off += (size_t)NCHUNK * 256 * 4;
    float* Cai = (float*)(w + off);      off += (size_t)NCHUNK * 256 * 4;
    __bf16* Ubf = (__bf16*)(w + off);    off += (size_t)L_SEQ * H_DIM * 2;  // 32 MB, reused as xs
    if (ws_size < off) return;  // fail loudly (output stays poisoned)

    float* Bu = (float*)d_out;  // 64 MB scratch: L x 2P f32, overwritten by final GEMM

    prep_kernel   <<<1,    256, 0, stream>>>(Lre, Lim, lst, par);
    build_B_kernel<<<512,  256, 0, stream>>>(Bre, Bim, par, Btm);
    build_C_kernel<<<512,  256, 0, stream>>>(Cre, Cim, Ctm);
    cast_u_kernel <<<8192, 256, 0, stream>>>((const float4*)u, (bf16x8*)Ubf, L_SEQ * H_DIM / 8);
    gemm_bt_kernel<false><<<dim3(256, 4), 256, 0, stream>>>(Ubf, Btm, Bu, nullptr, nullptr);
    scanA_kernel  <<<NCHUNK, 256, 0, stream>>>(Bu, par, Fr, Fi);
    scanB_kernel  <<<1,      256, 0, stream>>>(Fr, Fi, par, Car, Cai);
    scanC_kernel  <<<NCHUNK, 256, 0, stream>>>(Bu, par, Car, Cai, Ubf);
    gemm_bt_kernel<true><<<dim3(256, 4), 256, 0, stream>>>(Ubf, Ctm, (float*)d_out, Dv, u);
}

// Round 2
// 138.602 us; speedup vs baseline: 1.5491x; 1.5491x over previous
//
#include <hip/hip_runtime.h>
#include <cstdint>
#include <cstddef>

typedef __bf16 bf16x8 __attribute__((ext_vector_type(8)));
typedef float f32x4 __attribute__((ext_vector_type(4)));

#define L_SEQ 32768
#define H_DIM 512
#define P_DIM 256
#define NP2   512      // 2P = K and N of both GEMMs
#define CHUNK 32
#define NCHUNK 1024    // L / CHUNK
#define NSUPER 32      // NCHUNK / 32

__device__ __forceinline__ void gload_lds16(const void* g, void* l) {
    __builtin_amdgcn_global_load_lds(
        (const __attribute__((address_space(1))) void*)g,
        (__attribute__((address_space(3))) void*)l,
        16, 0, 0);
}

// ---------------- per-channel parameter precompute ----------------
// par layout (floats): [0]=Ar [256]=Ai [512]=coefR [768]=coefI
//                      [1024]=PowR (Lbar^32) [1280]=PowI
//                      [1536]=ldr (Re(Lambda)*step) [1792]=ldi (Im(Lambda)*step)
__global__ void prep_kernel(const float* __restrict__ Lre, const float* __restrict__ Lim,
                            const float* __restrict__ lstep, float* __restrict__ par) {
    int p = threadIdx.x;
    if (p >= P_DIM) return;
    float lr = fminf(Lre[p], -1e-4f);       // clip_eigs
    float li = Lim[p];
    float st = expf(lstep[p]);
    float ldr = lr * st;
    float ldi = li * st;
    float er = expf(ldr);
    float ar = er * cosf(ldi);
    float ai = er * sinf(ldi);
    // coeff = (Lambda_bar - 1) / Lambda
    float den = lr * lr + li * li;
    float mr = ar - 1.0f, mi = ai;
    float cr = (mr * lr + mi * li) / den;
    float ci = (mi * lr - mr * li) / den;
    // Lambda_bar^CHUNK = exp(CHUNK * Lambda * step)
    float e32  = expf((float)CHUNK * ldr);
    float ph32 = (float)CHUNK * ldi;
    float pr = e32 * cosf(ph32);
    float pi = e32 * sinf(ph32);
    par[p] = ar;        par[256 + p] = ai;
    par[512 + p] = cr;  par[768 + p] = ci;
    par[1024 + p] = pr; par[1280 + p] = pi;
    par[1536 + p] = ldr; par[1792 + p] = ldi;
}

// Bt[n][k]: n in [0,512) (re rows 0..255, im rows 256..511), k = h in [0,512)
__global__ void build_B_kernel(const float* __restrict__ Bre, const float* __restrict__ Bim,
                               const float* __restrict__ par, __bf16* __restrict__ Bt) {
    int idx = blockIdx.x * blockDim.x + threadIdx.x;   // [0, P*H)
    int p = idx >> 9;
    int h = idx & 511;
    float cr = par[512 + p], ci = par[768 + p];
    float br = Bre[idx], bi = Bim[idx];
    Bt[(size_t)p * NP2 + h]         = (__bf16)(cr * br - ci * bi);
    Bt[(size_t)(256 + p) * NP2 + h] = (__bf16)(cr * bi + ci * br);
}

// Ct[h][q]: q<256 -> 2*C_re[h][q], q>=256 -> -2*C_im[h][q-256]
__global__ void build_C_kernel(const float* __restrict__ Cre, const float* __restrict__ Cim,
                               __bf16* __restrict__ Ct) {
    int idx = blockIdx.x * blockDim.x + threadIdx.x;   // [0, H*P)
    int h = idx >> 8;
    int q = idx & 255;
    Ct[(size_t)h * NP2 + q]       = (__bf16)( 2.0f * Cre[idx]);
    Ct[(size_t)h * NP2 + 256 + q] = (__bf16)(-2.0f * Cim[idx]);
}

__global__ void cast_u_kernel(const float4* __restrict__ in, bf16x8* __restrict__ out, int n8) {
    int i = blockIdx.x * blockDim.x + threadIdx.x;
    if (i >= n8) return;
    float4 a = in[2 * i], b = in[2 * i + 1];
    bf16x8 v;
    v[0] = (__bf16)a.x; v[1] = (__bf16)a.y; v[2] = (__bf16)a.z; v[3] = (__bf16)a.w;
    v[4] = (__bf16)b.x; v[5] = (__bf16)b.y; v[6] = (__bf16)b.z; v[7] = (__bf16)b.w;
    out[i] = v;
}

// ---------------- GEMM: A(M,512) bf16 row-major  x  Bt(512,512) bf16 (N,K) ----------------
// 128x128 tile, BK=64, 4 waves each computing 64x64 (4x4 frags of 16x16x32 MFMA).
template<bool FUSE>
__global__ __launch_bounds__(256)
void gemm_bt_kernel(const __bf16* __restrict__ A, const __bf16* __restrict__ Bt,
                    float* __restrict__ Cout, const float* __restrict__ Dvec,
                    const float* __restrict__ U) {
    const int K = NP2, N = NP2;
    __shared__ __bf16 As[128 * 64];
    __shared__ __bf16 Bs[128 * 64];
    const int t = threadIdx.x;
    const int l = t & 63;
    const int w = t >> 6;
    const int wr = w >> 1, wc = w & 1;
    const int row0 = blockIdx.x * 128;
    const int col0 = blockIdx.y * 128;
    const int lr = l & 15;
    const int lk = (l >> 4) * 8;
    f32x4 acc[4][4] = {};

    for (int k0 = 0; k0 < K; k0 += 64) {
#pragma unroll
        for (int i = 0; i < 4; ++i) {
            int off = i * 256 + t;        // 16B-chunk id in tile, [0,1024)
            int r  = off >> 3;            // row in tile [0,128)
            int ce = (off & 7) * 8;       // bf16 col within row
            gload_lds16(A  + (size_t)(row0 + r) * K + (k0 + ce), As + off * 8);
            gload_lds16(Bt + (size_t)(col0 + r) * K + (k0 + ce), Bs + off * 8);
        }
        asm volatile("s_waitcnt vmcnt(0)" ::: "memory");
        __syncthreads();
#pragma unroll
        for (int kk = 0; kk < 64; kk += 32) {
            bf16x8 a[4], b[4];
#pragma unroll
            for (int m = 0; m < 4; ++m)
                a[m] = *reinterpret_cast<const bf16x8*>(As + (wr * 64 + m * 16 + lr) * 64 + kk + lk);
#pragma unroll
            for (int n = 0; n < 4; ++n)
                b[n] = *reinterpret_cast<const bf16x8*>(Bs + (wc * 64 + n * 16 + lr) * 64 + kk + lk);
#pragma unroll
            for (int m = 0; m < 4; ++m)
#pragma unroll
                for (int n = 0; n < 4; ++n)
                    acc[m][n] = __builtin_amdgcn_mfma_f32_16x16x32_bf16(a[m], b[n], acc[m][n], 0, 0, 0);
        }
        __syncthreads();
    }

    const int lg = (l >> 4) * 4;
#pragma unroll
    for (int m = 0; m < 4; ++m) {
#pragma unroll
        for (int n = 0; n < 4; ++n) {
            int col = col0 + wc * 64 + n * 16 + lr;
#pragma unroll
            for (int j = 0; j < 4; ++j) {
                int row = row0 + wr * 64 + m * 16 + lg + j;
                size_t o = (size_t)row * N + col;
                float v = acc[m][n][j];
                if (FUSE) v += Dvec[col] * U[o];
                Cout[o] = v;
            }
        }
    }
}

// ---------------- chunked scan ----------------
// Level 0: per-chunk (32 steps) totals F[g], g in [0,1024)
__global__ void scanA_kernel(const float* __restrict__ Bu, const float* __restrict__ par,
                             float* __restrict__ Fr, float* __restrict__ Fi) {
    int g = blockIdx.x;
    int p = threadIdx.x;
    float ar = par[p], ai = par[256 + p];
    const float* bu = Bu + (size_t)g * CHUNK * NP2;
    float xr = 0.f, xi = 0.f;
#pragma unroll 4
    for (int i = 0; i < CHUNK; ++i) {
        float br = bu[i * NP2 + p];
        float bi = bu[i * NP2 + 256 + p];
        float nr = fmaf(ar, xr, fmaf(-ai, xi, br));
        float ni = fmaf(ar, xi, fmaf( ai, xr, bi));
        xr = nr; xi = ni;
    }
    Fr[g * 256 + p] = xr;
    Fi[g * 256 + p] = xi;
}

// Level 1: 32 blocks; block s scans its 32 chunks. Writes within-super exclusive
// prefixes l[g] and super-chunk totals T[s].
__global__ void scanB1_kernel(const float* __restrict__ Fr, const float* __restrict__ Fi,
                              const float* __restrict__ par,
                              float* __restrict__ Lr, float* __restrict__ Li,
                              float* __restrict__ Tr, float* __restrict__ Ti) {
    int s = blockIdx.x;
    int p = threadIdx.x;
    float pr = par[1024 + p], pi = par[1280 + p];   // Lbar^32
    float er = 0.f, ei = 0.f;
    int base = s * 32;
#pragma unroll
    for (int j = 0; j < 32; ++j) {
        int g = base + j;
        Lr[g * 256 + p] = er;
        Li[g * 256 + p] = ei;
        float fr = Fr[g * 256 + p], fi = Fi[g * 256 + p];
        float nr = fmaf(pr, er, fmaf(-pi, ei, fr));
        float ni = fmaf(pr, ei, fmaf( pi, er, fi));
        er = nr; ei = ni;
    }
    Tr[s * 256 + p] = er;
    Ti[s * 256 + p] = ei;
}

// Level 2: 1 block, serial exclusive scan over 32 super-chunk totals with Lbar^1024.
__global__ void scanB2_kernel(const float* __restrict__ Tr, const float* __restrict__ Ti,
                              const float* __restrict__ par,
                              float* __restrict__ Er, float* __restrict__ Ei) {
    int p = threadIdx.x;
    float ldr = par[1536 + p], ldi = par[1792 + p];
    float e  = expf(1024.0f * ldr);
    float ph = 1024.0f * ldi;
    float qr = e * cosf(ph), qi = e * sinf(ph);     // Lbar^1024
    float er = 0.f, ei = 0.f;
#pragma unroll
    for (int s = 0; s < NSUPER; ++s) {
        Er[s * 256 + p] = er;
        Ei[s * 256 + p] = ei;
        float fr = Tr[s * 256 + p], fi = Ti[s * 256 + p];
        float nr = fmaf(qr, er, fmaf(-qi, ei, fr));
        float ni = fmaf(qr, ei, fmaf( qi, er, fi));
        er = nr; ei = ni;
    }
}

// Final: per-chunk replay with carry = Lbar^(32k) * E[s] + l[g]; writes xs (bf16).
__global__ void scanC_kernel(const float* __restrict__ Bu, const float* __restrict__ par,
                             const float* __restrict__ Lr, const float* __restrict__ Li,
                             const float* __restrict__ Er, const float* __restrict__ Ei,
                             __bf16* __restrict__ xs) {
    int g = blockIdx.x;
    int p = threadIdx.x;
    int s = g >> 5, k = g & 31;
    float ar = par[p], ai = par[256 + p];
    float ldr = par[1536 + p], ldi = par[1792 + p];
    float kk = (float)(32 * k);
    float e  = expf(kk * ldr);
    float ph = kk * ldi;
    float qr = e * cosf(ph), qi = e * sinf(ph);     // Lbar^(32k)
    float er = Er[s * 256 + p], ei = Ei[s * 256 + p];
    float lr0 = Lr[g * 256 + p], li0 = Li[g * 256 + p];
    float xr = fmaf(qr, er, fmaf(-qi, ei, lr0));
    float xi = fmaf(qr, ei, fmaf( qi, er, li0));
    const float* bu = Bu + (size_t)g * CHUNK * NP2;
    __bf16* xo = xs + (size_t)g * CHUNK * NP2;
#pragma unroll 4
    for (int i = 0; i < CHUNK; ++i) {
        float br = bu[i * NP2 + p];
        float bi = bu[i * NP2 + 256 + p];
        float nr = fmaf(ar, xr, fmaf(-ai, xi, br));
        float ni = fmaf(ar, xi, fmaf( ai, xr, bi));
        xr = nr; xi = ni;
        xo[i * NP2 + p]       = (__bf16)xr;
        xo[i * NP2 + 256 + p] = (__bf16)xi;
    }
}

extern "C" void kernel_launch(void* const* d_in, const int* in_sizes, int n_in,
                              void* d_out, int out_size, void* d_ws, size_t ws_size,
                              hipStream_t stream) {
    const float* u   = (const float*)d_in[0];
    const float* Lre = (const float*)d_in[1];
    const float* Lim = (const float*)d_in[2];
    const float* Bre = (const float*)d_in[3];
    const float* Bim = (const float*)d_in[4];
    const float* Cre = (const float*)d_in[5];
    const float* Cim = (const float*)d_in[6];
    const float* Dv  = (const float*)d_in[7];
    const float* lst = (const float*)d_in[8];

    char* w = (char*)d_ws;
    size_t off = 0;
    float* par = (float*)(w + off);      off += 16 * 1024;
    __bf16* Btm = (__bf16*)(w + off);    off += (size_t)NP2 * NP2 * 2;      // 512 KB
    __bf16* Ctm = (__bf16*)(w + off);    off += (size_t)NP2 * NP2 * 2;      // 512 KB
    float* Fr  = (float*)(w + off);      off += (size_t)NCHUNK * 256 * 4;   // 1 MB
    float* Fi  = (float*)(w + off);      off += (size_t)NCHUNK * 256 * 4;
    float* Lr  = (float*)(w + off);      off += (size_t)NCHUNK * 256 * 4;
    float* Li  = (float*)(w + off);      off += (size_t)NCHUNK * 256 * 4;
    float* Tr  = (float*)(w + off);      off += (size_t)NSUPER * 256 * 4;   // 32 KB
    float* Ti  = (float*)(w + off);      off += (size_t)NSUPER * 256 * 4;
    float* Er  = (float*)(w + off);      off += (size_t)NSUPER * 256 * 4;
    float* Ei  = (float*)(w + off);      off += (size_t)NSUPER * 256 * 4;
    __bf16* Ubf = (__bf16*)(w + off);    off += (size_t)L_SEQ * H_DIM * 2;  // 32 MB, reused as xs
    if (ws_size < off) return;  // fail loudly (output stays poisoned)

    float* Bu = (float*)d_out;  // 64 MB scratch: L x 2P f32, overwritten by final GEMM

    prep_kernel   <<<1,    256, 0, stream>>>(Lre, Lim, lst, par);
    build_B_kernel<<<512,  256, 0, stream>>>(Bre, Bim, par, Btm);
    build_C_kernel<<<512,  256, 0, stream>>>(Cre, Cim, Ctm);
    cast_u_kernel <<<8192, 256, 0, stream>>>((const float4*)u, (bf16x8*)Ubf, L_SEQ * H_DIM / 8);
    gemm_bt_kernel<false><<<dim3(256, 4), 256, 0, stream>>>(Ubf, Btm, Bu, nullptr, nullptr);
    scanA_kernel  <<<NCHUNK, 256, 0, stream>>>(Bu, par, Fr, Fi);
    scanB1_kernel <<<NSUPER, 256, 0, stream>>>(Fr, Fi, par, Lr, Li, Tr, Ti);
    scanB2_kernel <<<1,      256, 0, stream>>>(Tr, Ti, par, Er, Ei);
    scanC_kernel  <<<NCHUNK, 256, 0, stream>>>(Bu, par, Lr, Li, Er, Ei, Ubf);
    gemm_bt_kernel<true><<<dim3(256, 4), 256, 0, stream>>>(Ubf, Ctm, (float*)d_out, Dv, u);
}

// Round 3
// 132.111 us; speedup vs baseline: 1.6252x; 1.0491x over previous
//
#include <hip/hip_runtime.h>
#include <cstdint>
#include <cstddef>

typedef __bf16 bf16x8 __attribute__((ext_vector_type(8)));
typedef float f32x4 __attribute__((ext_vector_type(4)));

#define L_SEQ 32768
#define H_DIM 512
#define P_DIM 256
#define NP2   512      // 2P = K and N of both GEMMs
#define CHUNK 32
#define NCHUNK 1024    // L / CHUNK
#define NSUPER 32      // NCHUNK / 32

__device__ __forceinline__ void gload_lds16(const void* g, void* l) {
    __builtin_amdgcn_global_load_lds(
        (const __attribute__((address_space(1))) void*)g,
        (__attribute__((address_space(3))) void*)l,
        16, 0, 0);
}

// ---------------- per-channel parameter precompute ----------------
// par layout (floats): [0]=Ar [256]=Ai [512]=coefR [768]=coefI
//                      [1024]=PowR (Lbar^32) [1280]=PowI
//                      [1536]=ldr (Re(Lambda)*step) [1792]=ldi (Im(Lambda)*step)
__global__ void prep_kernel(const float* __restrict__ Lre, const float* __restrict__ Lim,
                            const float* __restrict__ lstep, float* __restrict__ par) {
    int p = threadIdx.x;
    if (p >= P_DIM) return;
    float lr = fminf(Lre[p], -1e-4f);       // clip_eigs
    float li = Lim[p];
    float st = expf(lstep[p]);
    float ldr = lr * st;
    float ldi = li * st;
    float er = expf(ldr);
    float ar = er * cosf(ldi);
    float ai = er * sinf(ldi);
    // coeff = (Lambda_bar - 1) / Lambda
    float den = lr * lr + li * li;
    float mr = ar - 1.0f, mi = ai;
    float cr = (mr * lr + mi * li) / den;
    float ci = (mi * lr - mr * li) / den;
    // Lambda_bar^CHUNK = exp(CHUNK * Lambda * step)
    float e32  = expf((float)CHUNK * ldr);
    float ph32 = (float)CHUNK * ldi;
    float pr = e32 * cosf(ph32);
    float pi = e32 * sinf(ph32);
    par[p] = ar;        par[256 + p] = ai;
    par[512 + p] = cr;  par[768 + p] = ci;
    par[1024 + p] = pr; par[1280 + p] = pi;
    par[1536 + p] = ldr; par[1792 + p] = ldi;
}

// Bt[n][k]: n in [0,512) (re rows 0..255, im rows 256..511), k = h in [0,512)
__global__ void build_B_kernel(const float* __restrict__ Bre, const float* __restrict__ Bim,
                               const float* __restrict__ par, __bf16* __restrict__ Bt) {
    int idx = blockIdx.x * blockDim.x + threadIdx.x;   // [0, P*H)
    int p = idx >> 9;
    int h = idx & 511;
    float cr = par[512 + p], ci = par[768 + p];
    float br = Bre[idx], bi = Bim[idx];
    Bt[(size_t)p * NP2 + h]         = (__bf16)(cr * br - ci * bi);
    Bt[(size_t)(256 + p) * NP2 + h] = (__bf16)(cr * bi + ci * br);
}

// Ct[h][q]: q<256 -> 2*C_re[h][q], q>=256 -> -2*C_im[h][q-256]
__global__ void build_C_kernel(const float* __restrict__ Cre, const float* __restrict__ Cim,
                               __bf16* __restrict__ Ct) {
    int idx = blockIdx.x * blockDim.x + threadIdx.x;   // [0, H*P)
    int h = idx >> 8;
    int q = idx & 255;
    Ct[(size_t)h * NP2 + q]       = (__bf16)( 2.0f * Cre[idx]);
    Ct[(size_t)h * NP2 + 256 + q] = (__bf16)(-2.0f * Cim[idx]);
}

__global__ void cast_u_kernel(const float4* __restrict__ in, bf16x8* __restrict__ out, int n8) {
    int i = blockIdx.x * blockDim.x + threadIdx.x;
    if (i >= n8) return;
    float4 a = in[2 * i], b = in[2 * i + 1];
    bf16x8 v;
    v[0] = (__bf16)a.x; v[1] = (__bf16)a.y; v[2] = (__bf16)a.z; v[3] = (__bf16)a.w;
    v[4] = (__bf16)b.x; v[5] = (__bf16)b.y; v[6] = (__bf16)b.z; v[7] = (__bf16)b.w;
    out[i] = v;
}

// ---------------- GEMM: A(M,512) bf16 row-major  x  Bt(512,512) bf16 (N,K) ----------------
// 128x128 tile, BK=64, 4 waves each computing 64x64 (4x4 frags of 16x16x32 MFMA).
// 2-phase pipeline (T3 minimum): LDS double-buffer, STAGE(t+1) issued before
// COMPUTE(t), counted vmcnt(8) + raw s_barrier (no compiler vmcnt(0) drain).
template<bool FUSE>
__global__ __launch_bounds__(256)
void gemm_bt_kernel(const __bf16* __restrict__ A, const __bf16* __restrict__ Bt,
                    float* __restrict__ Cout, const float* __restrict__ Dvec,
                    const float* __restrict__ U) {
    const int K = NP2, N = NP2;
    __shared__ __align__(16) __bf16 As[2][128 * 64];
    __shared__ __align__(16) __bf16 Bs[2][128 * 64];
    const int t = threadIdx.x;
    const int l = t & 63;
    const int w = t >> 6;
    const int wr = w >> 1, wc = w & 1;
    const int row0 = blockIdx.x * 128;
    const int col0 = blockIdx.y * 128;
    const int lr = l & 15;
    const int lk = (l >> 4) * 8;
    f32x4 acc[4][4] = {};

    // per-wave: 8 gload_lds instructions per STAGE
    auto STAGE = [&](int buf, int k0) {
#pragma unroll
        for (int i = 0; i < 4; ++i) {
            int off = i * 256 + t;        // 16B-chunk id in tile, [0,1024)
            int r  = off >> 3;            // row in tile [0,128)
            int ce = (off & 7) * 8;       // bf16 col within row
            gload_lds16(A  + (size_t)(row0 + r) * K + (k0 + ce), &As[buf][off * 8]);
            gload_lds16(Bt + (size_t)(col0 + r) * K + (k0 + ce), &Bs[buf][off * 8]);
        }
    };

    auto COMPUTE = [&](int buf) {
#pragma unroll
        for (int kk = 0; kk < 64; kk += 32) {
            bf16x8 a[4], b[4];
#pragma unroll
            for (int m = 0; m < 4; ++m)
                a[m] = *reinterpret_cast<const bf16x8*>(&As[buf][(wr * 64 + m * 16 + lr) * 64 + kk + lk]);
#pragma unroll
            for (int n = 0; n < 4; ++n)
                b[n] = *reinterpret_cast<const bf16x8*>(&Bs[buf][(wc * 64 + n * 16 + lr) * 64 + kk + lk]);
#pragma unroll
            for (int m = 0; m < 4; ++m)
#pragma unroll
                for (int n = 0; n < 4; ++n)
                    acc[m][n] = __builtin_amdgcn_mfma_f32_16x16x32_bf16(a[m], b[n], acc[m][n], 0, 0, 0);
        }
    };

    STAGE(0, 0);
    int cur = 0;
#pragma unroll
    for (int k0 = 64; k0 < K; k0 += 64) {       // 7 iterations
        STAGE(cur ^ 1, k0);                     // next tile in flight
        asm volatile("s_waitcnt vmcnt(8)" ::: "memory");   // prev tile's 8 loads done
        __builtin_amdgcn_s_barrier();
        __builtin_amdgcn_sched_barrier(0);
        COMPUTE(cur);
        __builtin_amdgcn_sched_barrier(0);
        __builtin_amdgcn_s_barrier();           // all waves done reading buf[cur]
        __builtin_amdgcn_sched_barrier(0);
        cur ^= 1;
    }
    asm volatile("s_waitcnt vmcnt(0)" ::: "memory");
    __builtin_amdgcn_s_barrier();
    __builtin_amdgcn_sched_barrier(0);
    COMPUTE(cur);

    const int lg = (l >> 4) * 4;
#pragma unroll
    for (int m = 0; m < 4; ++m) {
#pragma unroll
        for (int n = 0; n < 4; ++n) {
            int col = col0 + wc * 64 + n * 16 + lr;
#pragma unroll
            for (int j = 0; j < 4; ++j) {
                int row = row0 + wr * 64 + m * 16 + lg + j;
                size_t o = (size_t)row * N + col;
                float v = acc[m][n][j];
                if (FUSE) v += Dvec[col] * U[o];
                Cout[o] = v;
            }
        }
    }
}

// ---------------- chunked scan ----------------
// Level 0: per-chunk (32 steps) totals F[g], g in [0,1024)
__global__ void scanA_kernel(const float* __restrict__ Bu, const float* __restrict__ par,
                             float* __restrict__ Fr, float* __restrict__ Fi) {
    int g = blockIdx.x;
    int p = threadIdx.x;
    float ar = par[p], ai = par[256 + p];
    const float* bu = Bu + (size_t)g * CHUNK * NP2;
    float xr = 0.f, xi = 0.f;
#pragma unroll 4
    for (int i = 0; i < CHUNK; ++i) {
        float br = bu[i * NP2 + p];
        float bi = bu[i * NP2 + 256 + p];
        float nr = fmaf(ar, xr, fmaf(-ai, xi, br));
        float ni = fmaf(ar, xi, fmaf( ai, xr, bi));
        xr = nr; xi = ni;
    }
    Fr[g * 256 + p] = xr;
    Fi[g * 256 + p] = xi;
}

// Level 1: 32 blocks; block s scans its 32 chunks. Writes within-super exclusive
// prefixes l[g] and super-chunk totals T[s].
__global__ void scanB1_kernel(const float* __restrict__ Fr, const float* __restrict__ Fi,
                              const float* __restrict__ par,
                              float* __restrict__ Lr, float* __restrict__ Li,
                              float* __restrict__ Tr, float* __restrict__ Ti) {
    int s = blockIdx.x;
    int p = threadIdx.x;
    float pr = par[1024 + p], pi = par[1280 + p];   // Lbar^32
    float er = 0.f, ei = 0.f;
    int base = s * 32;
#pragma unroll
    for (int j = 0; j < 32; ++j) {
        int g = base + j;
        Lr[g * 256 + p] = er;
        Li[g * 256 + p] = ei;
        float fr = Fr[g * 256 + p], fi = Fi[g * 256 + p];
        float nr = fmaf(pr, er, fmaf(-pi, ei, fr));
        float ni = fmaf(pr, ei, fmaf( pi, er, fi));
        er = nr; ei = ni;
    }
    Tr[s * 256 + p] = er;
    Ti[s * 256 + p] = ei;
}

// Level 2: 1 block, serial exclusive scan over 32 super-chunk totals with Lbar^1024.
__global__ void scanB2_kernel(const float* __restrict__ Tr, const float* __restrict__ Ti,
                              const float* __restrict__ par,
                              float* __restrict__ Er, float* __restrict__ Ei) {
    int p = threadIdx.x;
    float ldr = par[1536 + p], ldi = par[1792 + p];
    float e  = expf(1024.0f * ldr);
    float ph = 1024.0f * ldi;
    float qr = e * cosf(ph), qi = e * sinf(ph);     // Lbar^1024
    float er = 0.f, ei = 0.f;
#pragma unroll
    for (int s = 0; s < NSUPER; ++s) {
        Er[s * 256 + p] = er;
        Ei[s * 256 + p] = ei;
        float fr = Tr[s * 256 + p], fi = Ti[s * 256 + p];
        float nr = fmaf(qr, er, fmaf(-qi, ei, fr));
        float ni = fmaf(qr, ei, fmaf( qi, er, fi));
        er = nr; ei = ni;
    }
}

// Final: per-chunk replay with carry = Lbar^(32k) * E[s] + l[g]; writes xs (bf16).
__global__ void scanC_kernel(const float* __restrict__ Bu, const float* __restrict__ par,
                             const float* __restrict__ Lr, const float* __restrict__ Li,
                             const float* __restrict__ Er, const float* __restrict__ Ei,
                             __bf16* __restrict__ xs) {
    int g = blockIdx.x;
    int p = threadIdx.x;
    int s = g >> 5, k = g & 31;
    float ar = par[p], ai = par[256 + p];
    float ldr = par[1536 + p], ldi = par[1792 + p];
    float kk = (float)(32 * k);
    float e  = expf(kk * ldr);
    float ph = kk * ldi;
    float qr = e * cosf(ph), qi = e * sinf(ph);     // Lbar^(32k)
    float er = Er[s * 256 + p], ei = Ei[s * 256 + p];
    float lr0 = Lr[g * 256 + p], li0 = Li[g * 256 + p];
    float xr = fmaf(qr, er, fmaf(-qi, ei, lr0));
    float xi = fmaf(qr, ei, fmaf( qi, er, li0));
    const float* bu = Bu + (size_t)g * CHUNK * NP2;
    __bf16* xo = xs + (size_t)g * CHUNK * NP2;
#pragma unroll 4
    for (int i = 0; i < CHUNK; ++i) {
        float br = bu[i * NP2 + p];
        float bi = bu[i * NP2 + 256 + p];
        float nr = fmaf(ar, xr, fmaf(-ai, xi, br));
        float ni = fmaf(ar, xi, fmaf( ai, xr, bi));
        xr = nr; xi = ni;
        xo[i * NP2 + p]       = (__bf16)xr;
        xo[i * NP2 + 256 + p] = (__bf16)xi;
    }
}

extern "C" void kernel_launch(void* const* d_in, const int* in_sizes, int n_in,
                              void* d_out, int out_size, void* d_ws, size_t ws_size,
                              hipStream_t stream) {
    const float* u   = (const float*)d_in[0];
    const float* Lre = (const float*)d_in[1];
    const float* Lim = (const float*)d_in[2];
    const float* Bre = (const float*)d_in[3];
    const float* Bim = (const float*)d_in[4];
    const float* Cre = (const float*)d_in[5];
    const float* Cim = (const float*)d_in[6];
    const float* Dv  = (const float*)d_in[7];
    const float* lst = (const float*)d_in[8];

    char* w = (char*)d_ws;
    size_t off = 0;
    float* par = (float*)(w + off);      off += 16 * 1024;
    __bf16* Btm = (__bf16*)(w + off);    off += (size_t)NP2 * NP2 * 2;      // 512 KB
    __bf16* Ctm = (__bf16*)(w + off);    off += (size_t)NP2 * NP2 * 2;      // 512 KB
    float* Fr  = (float*)(w + off);      off += (size_t)NCHUNK * 256 * 4;   // 1 MB
    float* Fi  = (float*)(w + off);      off += (size_t)NCHUNK * 256 * 4;
    float* Lr  = (float*)(w + off);      off += (size_t)NCHUNK * 256 * 4;
    float* Li  = (float*)(w + off);      off += (size_t)NCHUNK * 256 * 4;
    float* Tr  = (float*)(w + off);      off += (size_t)NSUPER * 256 * 4;   // 32 KB
    float* Ti  = (float*)(w + off);      off += (size_t)NSUPER * 256 * 4;
    float* Er  = (float*)(w + off);      off += (size_t)NSUPER * 256 * 4;
    float* Ei  = (float*)(w + off);      off += (size_t)NSUPER * 256 * 4;
    __bf16* Ubf = (__bf16*)(w + off);    off += (size_t)L_SEQ * H_DIM * 2;  // 32 MB, reused as xs
    if (ws_size < off) return;  // fail loudly (output stays poisoned)

    float* Bu = (float*)d_out;  // 64 MB scratch: L x 2P f32, overwritten by final GEMM

    prep_kernel   <<<1,    256, 0, stream>>>(Lre, Lim, lst, par);
    build_B_kernel<<<512,  256, 0, stream>>>(Bre, Bim, par, Btm);
    build_C_kernel<<<512,  256, 0, stream>>>(Cre, Cim, Ctm);
    cast_u_kernel <<<8192, 256, 0, stream>>>((const float4*)u, (bf16x8*)Ubf, L_SEQ * H_DIM / 8);
    gemm_bt_kernel<false><<<dim3(256, 4), 256, 0, stream>>>(Ubf, Btm, Bu, nullptr, nullptr);
    scanA_kernel  <<<NCHUNK, 256, 0, stream>>>(Bu, par, Fr, Fi);
    scanB1_kernel <<<NSUPER, 256, 0, stream>>>(Fr, Fi, par, Lr, Li, Tr, Ti);
    scanB2_kernel <<<1,      256, 0, stream>>>(Tr, Ti, par, Er, Ei);
    scanC_kernel  <<<NCHUNK, 256, 0, stream>>>(Bu, par, Lr, Li, Er, Ei, Ubf);
    gemm_bt_kernel<true><<<dim3(256, 4), 256, 0, stream>>>(Ubf, Ctm, (float*)d_out, Dv, u);
}

// Round 4
// 108.654 us; speedup vs baseline: 1.9760x; 1.2159x over previous
//
#include <hip/hip_runtime.h>
#include <cstdint>
#include <cstddef>

typedef __bf16 bf16x8 __attribute__((ext_vector_type(8)));
typedef float f32x4 __attribute__((ext_vector_type(4)));

#define L_SEQ 32768
#define H_DIM 512
#define P_DIM 256
#define NP2   512      // 2P = K and N of both GEMMs
#define CHUNK 32
#define NCHUNK 1024    // L / CHUNK
#define NSUPER 32      // NCHUNK / 32

__device__ __forceinline__ void gload_lds16(const void* g, void* l) {
    __builtin_amdgcn_global_load_lds(
        (const __attribute__((address_space(1))) void*)g,
        (__attribute__((address_space(3))) void*)l,
        16, 0, 0);
}

// ---------------- per-channel parameter precompute ----------------
// par layout (floats): [0]=Ar [256]=Ai [512]=coefR [768]=coefI
//                      [1024]=PowR (Lbar^32) [1280]=PowI
//                      [1536]=ldr (Re(Lambda)*step) [1792]=ldi (Im(Lambda)*step)
__global__ void prep_kernel(const float* __restrict__ Lre, const float* __restrict__ Lim,
                            const float* __restrict__ lstep, float* __restrict__ par) {
    int p = threadIdx.x;
    if (p >= P_DIM) return;
    float lr = fminf(Lre[p], -1e-4f);       // clip_eigs
    float li = Lim[p];
    float st = expf(lstep[p]);
    float ldr = lr * st;
    float ldi = li * st;
    float er = expf(ldr);
    float ar = er * cosf(ldi);
    float ai = er * sinf(ldi);
    // coeff = (Lambda_bar - 1) / Lambda
    float den = lr * lr + li * li;
    float mr = ar - 1.0f, mi = ai;
    float cr = (mr * lr + mi * li) / den;
    float ci = (mi * lr - mr * li) / den;
    // Lambda_bar^CHUNK = exp(CHUNK * Lambda * step)
    float e32  = expf((float)CHUNK * ldr);
    float ph32 = (float)CHUNK * ldi;
    float pr = e32 * cosf(ph32);
    float pi = e32 * sinf(ph32);
    par[p] = ar;        par[256 + p] = ai;
    par[512 + p] = cr;  par[768 + p] = ci;
    par[1024 + p] = pr; par[1280 + p] = pi;
    par[1536 + p] = ldr; par[1792 + p] = ldi;
}

// Bt[n][k]: n in [0,512) (re rows 0..255, im rows 256..511), k = h in [0,512)
__global__ void build_B_kernel(const float* __restrict__ Bre, const float* __restrict__ Bim,
                               const float* __restrict__ par, __bf16* __restrict__ Bt) {
    int idx = blockIdx.x * blockDim.x + threadIdx.x;   // [0, P*H)
    int p = idx >> 9;
    int h = idx & 511;
    float cr = par[512 + p], ci = par[768 + p];
    float br = Bre[idx], bi = Bim[idx];
    Bt[(size_t)p * NP2 + h]         = (__bf16)(cr * br - ci * bi);
    Bt[(size_t)(256 + p) * NP2 + h] = (__bf16)(cr * bi + ci * br);
}

// Ct[h][q]: q<256 -> 2*C_re[h][q], q>=256 -> -2*C_im[h][q-256]
__global__ void build_C_kernel(const float* __restrict__ Cre, const float* __restrict__ Cim,
                               __bf16* __restrict__ Ct) {
    int idx = blockIdx.x * blockDim.x + threadIdx.x;   // [0, H*P)
    int h = idx >> 8;
    int q = idx & 255;
    Ct[(size_t)h * NP2 + q]       = (__bf16)( 2.0f * Cre[idx]);
    Ct[(size_t)h * NP2 + 256 + q] = (__bf16)(-2.0f * Cim[idx]);
}

__global__ void cast_u_kernel(const float4* __restrict__ in, bf16x8* __restrict__ out, int n8) {
    int i = blockIdx.x * blockDim.x + threadIdx.x;
    if (i >= n8) return;
    float4 a = in[2 * i], b = in[2 * i + 1];
    bf16x8 v;
    v[0] = (__bf16)a.x; v[1] = (__bf16)a.y; v[2] = (__bf16)a.z; v[3] = (__bf16)a.w;
    v[4] = (__bf16)b.x; v[5] = (__bf16)b.y; v[6] = (__bf16)b.z; v[7] = (__bf16)b.w;
    out[i] = v;
}

// ---------------- GEMM: A(M,512) bf16 row-major  x  Bt(512,512) bf16 (N,K) ----------------
// 128x128 tile, BK=64, 4 waves each computing 64x64 (4x4 frags of 16x16x32 MFMA).
// 2-phase pipeline: LDS dbuf, counted vmcnt(8), raw s_barrier.
// T2 XOR-swizzle (slot ^= row&7): applied on the GLOBAL source column during
// gload_lds staging (LDS dest stays linear, rule #21) and on the LDS read addr.
// Bijective XCD swizzle: each XCD gets 32 contiguous row-panels x 4 col-tiles.
// FUSE=false: writes bf16 (Bu). FUSE=true: writes f32 d_out += D*u.
template<bool FUSE>
__global__ __launch_bounds__(256)
void gemm_bt_kernel(const __bf16* __restrict__ A, const __bf16* __restrict__ Bt,
                    void* __restrict__ CoutV, const float* __restrict__ Dvec,
                    const float* __restrict__ U) {
    const int K = NP2, N = NP2;
    __shared__ __align__(16) __bf16 As[2][128 * 64];
    __shared__ __align__(16) __bf16 Bs[2][128 * 64];
    const int t = threadIdx.x;
    const int l = t & 63;
    const int w = t >> 6;
    const int wr = w >> 1, wc = w & 1;
    // XCD-aware bijective remap: 1024 blocks = 8 XCDs * 128 slots
    const int b    = blockIdx.x;
    const int n_sw = (b & 7) * 128 + (b >> 3);
    const int row0 = (n_sw >> 2) * 128;
    const int col0 = (n_sw & 3) * 128;
    const int lr = l & 15;
    const int lk = (l >> 4) * 8;
    f32x4 acc[4][4] = {};

    // per-wave: 8 gload_lds instructions per STAGE
    auto STAGE = [&](int buf, int k0) {
#pragma unroll
        for (int i = 0; i < 4; ++i) {
            int off = i * 256 + t;        // 16B-chunk id in tile, [0,1024)
            int r  = off >> 3;            // row in tile [0,128)
            int ce = ((off & 7) ^ (r & 7)) * 8;   // swizzled source col (bf16 units)
            gload_lds16(A  + (size_t)(row0 + r) * K + (k0 + ce), &As[buf][off * 8]);
            gload_lds16(Bt + (size_t)(col0 + r) * K + (k0 + ce), &Bs[buf][off * 8]);
        }
    };

    auto COMPUTE = [&](int buf) {
#pragma unroll
        for (int kk = 0; kk < 64; kk += 32) {
            bf16x8 a[4], b2[4];
            const int ls = (kk + lk) >> 3;        // logical 16B slot [0,8)
#pragma unroll
            for (int m = 0; m < 4; ++m) {
                int row = wr * 64 + m * 16 + lr;
                a[m] = *reinterpret_cast<const bf16x8*>(&As[buf][row * 64 + ((ls ^ (row & 7)) << 3)]);
            }
#pragma unroll
            for (int n = 0; n < 4; ++n) {
                int row = wc * 64 + n * 16 + lr;
                b2[n] = *reinterpret_cast<const bf16x8*>(&Bs[buf][row * 64 + ((ls ^ (row & 7)) << 3)]);
            }
            __builtin_amdgcn_s_setprio(1);
#pragma unroll
            for (int m = 0; m < 4; ++m)
#pragma unroll
                for (int n = 0; n < 4; ++n)
                    acc[m][n] = __builtin_amdgcn_mfma_f32_16x16x32_bf16(a[m], b2[n], acc[m][n], 0, 0, 0);
            __builtin_amdgcn_s_setprio(0);
        }
    };

    STAGE(0, 0);
    int cur = 0;
#pragma unroll
    for (int k0 = 64; k0 < K; k0 += 64) {       // 7 iterations
        STAGE(cur ^ 1, k0);                     // next tile in flight
        asm volatile("s_waitcnt vmcnt(8)" ::: "memory");   // prev tile's 8 loads done
        __builtin_amdgcn_s_barrier();
        __builtin_amdgcn_sched_barrier(0);
        COMPUTE(cur);
        __builtin_amdgcn_sched_barrier(0);
        __builtin_amdgcn_s_barrier();           // all waves done reading buf[cur]
        __builtin_amdgcn_sched_barrier(0);
        cur ^= 1;
    }
    asm volatile("s_waitcnt vmcnt(0)" ::: "memory");
    __builtin_amdgcn_s_barrier();
    __builtin_amdgcn_sched_barrier(0);
    COMPUTE(cur);

    const int lg = (l >> 4) * 4;
#pragma unroll
    for (int m = 0; m < 4; ++m) {
#pragma unroll
        for (int n = 0; n < 4; ++n) {
            int col = col0 + wc * 64 + n * 16 + lr;
#pragma unroll
            for (int j = 0; j < 4; ++j) {
                int row = row0 + wr * 64 + m * 16 + lg + j;
                size_t o = (size_t)row * N + col;
                if (FUSE) {
                    ((float*)CoutV)[o] = acc[m][n][j] + Dvec[col] * U[o];
                } else {
                    ((__bf16*)CoutV)[o] = (__bf16)acc[m][n][j];
                }
            }
        }
    }
}

// ---------------- chunked scan (Bu is bf16 now) ----------------
// Level 0: per-chunk (32 steps) totals F[g], g in [0,1024)
__global__ void scanA_kernel(const __bf16* __restrict__ Bu, const float* __restrict__ par,
                             float* __restrict__ Fr, float* __restrict__ Fi) {
    int g = blockIdx.x;
    int p = threadIdx.x;
    float ar = par[p], ai = par[256 + p];
    const __bf16* bu = Bu + (size_t)g * CHUNK * NP2;
    float xr = 0.f, xi = 0.f;
#pragma unroll 4
    for (int i = 0; i < CHUNK; ++i) {
        float br = (float)bu[i * NP2 + p];
        float bi = (float)bu[i * NP2 + 256 + p];
        float nr = fmaf(ar, xr, fmaf(-ai, xi, br));
        float ni = fmaf(ar, xi, fmaf( ai, xr, bi));
        xr = nr; xi = ni;
    }
    Fr[g * 256 + p] = xr;
    Fi[g * 256 + p] = xi;
}

// Level 1: 32 blocks; block s scans its 32 chunks. Writes within-super exclusive
// prefixes l[g] and super-chunk totals T[s].
__global__ void scanB1_kernel(const float* __restrict__ Fr, const float* __restrict__ Fi,
                              const float* __restrict__ par,
                              float* __restrict__ Lr, float* __restrict__ Li,
                              float* __restrict__ Tr, float* __restrict__ Ti) {
    int s = blockIdx.x;
    int p = threadIdx.x;
    float pr = par[1024 + p], pi = par[1280 + p];   // Lbar^32
    float er = 0.f, ei = 0.f;
    int base = s * 32;
#pragma unroll
    for (int j = 0; j < 32; ++j) {
        int g = base + j;
        Lr[g * 256 + p] = er;
        Li[g * 256 + p] = ei;
        float fr = Fr[g * 256 + p], fi = Fi[g * 256 + p];
        float nr = fmaf(pr, er, fmaf(-pi, ei, fr));
        float ni = fmaf(pr, ei, fmaf( pi, er, fi));
        er = nr; ei = ni;
    }
    Tr[s * 256 + p] = er;
    Ti[s * 256 + p] = ei;
}

// Level 2: 1 block, serial exclusive scan over 32 super-chunk totals with Lbar^1024.
__global__ void scanB2_kernel(const float* __restrict__ Tr, const float* __restrict__ Ti,
                              const float* __restrict__ par,
                              float* __restrict__ Er, float* __restrict__ Ei) {
    int p = threadIdx.x;
    float ldr = par[1536 + p], ldi = par[1792 + p];
    float e  = expf(1024.0f * ldr);
    float ph = 1024.0f * ldi;
    float qr = e * cosf(ph), qi = e * sinf(ph);     // Lbar^1024
    float er = 0.f, ei = 0.f;
#pragma unroll
    for (int s = 0; s < NSUPER; ++s) {
        Er[s * 256 + p] = er;
        Ei[s * 256 + p] = ei;
        float fr = Tr[s * 256 + p], fi = Ti[s * 256 + p];
        float nr = fmaf(qr, er, fmaf(-qi, ei, fr));
        float ni = fmaf(qr, ei, fmaf( qi, er, fi));
        er = nr; ei = ni;
    }
}

// Final: per-chunk replay with carry = Lbar^(32k) * E[s] + l[g]; writes xs (bf16).
__global__ void scanC_kernel(const __bf16* __restrict__ Bu, const float* __restrict__ par,
                             const float* __restrict__ Lr, const float* __restrict__ Li,
                             const float* __restrict__ Er, const float* __restrict__ Ei,
                             __bf16* __restrict__ xs) {
    int g = blockIdx.x;
    int p = threadIdx.x;
    int s = g >> 5, k = g & 31;
    float ar = par[p], ai = par[256 + p];
    float ldr = par[1536 + p], ldi = par[1792 + p];
    float kk = (float)(32 * k);
    float e  = expf(kk * ldr);
    float ph = kk * ldi;
    float qr = e * cosf(ph), qi = e * sinf(ph);     // Lbar^(32k)
    float er = Er[s * 256 + p], ei = Ei[s * 256 + p];
    float lr0 = Lr[g * 256 + p], li0 = Li[g * 256 + p];
    float xr = fmaf(qr, er, fmaf(-qi, ei, lr0));
    float xi = fmaf(qr, ei, fmaf( qi, er, li0));
    const __bf16* bu = Bu + (size_t)g * CHUNK * NP2;
    __bf16* xo = xs + (size_t)g * CHUNK * NP2;
#pragma unroll 4
    for (int i = 0; i < CHUNK; ++i) {
        float br = (float)bu[i * NP2 + p];
        float bi = (float)bu[i * NP2 + 256 + p];
        float nr = fmaf(ar, xr, fmaf(-ai, xi, br));
        float ni = fmaf(ar, xi, fmaf( ai, xr, bi));
        xr = nr; xi = ni;
        xo[i * NP2 + p]       = (__bf16)xr;
        xo[i * NP2 + 256 + p] = (__bf16)xi;
    }
}

extern "C" void kernel_launch(void* const* d_in, const int* in_sizes, int n_in,
                              void* d_out, int out_size, void* d_ws, size_t ws_size,
                              hipStream_t stream) {
    const float* u   = (const float*)d_in[0];
    const float* Lre = (const float*)d_in[1];
    const float* Lim = (const float*)d_in[2];
    const float* Bre = (const float*)d_in[3];
    const float* Bim = (const float*)d_in[4];
    const float* Cre = (const float*)d_in[5];
    const float* Cim = (const float*)d_in[6];
    const float* Dv  = (const float*)d_in[7];
    const float* lst = (const float*)d_in[8];

    char* w = (char*)d_ws;
    size_t off = 0;
    float* par = (float*)(w + off);      off += 16 * 1024;
    __bf16* Btm = (__bf16*)(w + off);    off += (size_t)NP2 * NP2 * 2;      // 512 KB
    __bf16* Ctm = (__bf16*)(w + off);    off += (size_t)NP2 * NP2 * 2;      // 512 KB
    float* Fr  = (float*)(w + off);      off += (size_t)NCHUNK * 256 * 4;   // 1 MB
    float* Fi  = (float*)(w + off);      off += (size_t)NCHUNK * 256 * 4;
    float* Lr  = (float*)(w + off);      off += (size_t)NCHUNK * 256 * 4;
    float* Li  = (float*)(w + off);      off += (size_t)NCHUNK * 256 * 4;
    float* Tr  = (float*)(w + off);      off += (size_t)NSUPER * 256 * 4;   // 32 KB
    float* Ti  = (float*)(w + off);      off += (size_t)NSUPER * 256 * 4;
    float* Er  = (float*)(w + off);      off += (size_t)NSUPER * 256 * 4;
    float* Ei  = (float*)(w + off);      off += (size_t)NSUPER * 256 * 4;
    __bf16* Ubf = (__bf16*)(w + off);    off += (size_t)L_SEQ * H_DIM * 2;  // 32 MB, reused as xs
    if (ws_size < off) return;  // fail loudly (output stays poisoned)

    // Bu: bf16 L x 2P (32 MB) in the lower half of d_out; GEMM2 overwrites
    // all of d_out (f32 output) afterwards.
    __bf16* Bu = (__bf16*)d_out;

    prep_kernel   <<<1,    256, 0, stream>>>(Lre, Lim, lst, par);
    build_B_kernel<<<512,  256, 0, stream>>>(Bre, Bim, par, Btm);
    build_C_kernel<<<512,  256, 0, stream>>>(Cre, Cim, Ctm);
    cast_u_kernel <<<8192, 256, 0, stream>>>((const float4*)u, (bf16x8*)Ubf, L_SEQ * H_DIM / 8);
    gemm_bt_kernel<false><<<1024, 256, 0, stream>>>(Ubf, Btm, (void*)Bu, nullptr, nullptr);
    scanA_kernel  <<<NCHUNK, 256, 0, stream>>>(Bu, par, Fr, Fi);
    scanB1_kernel <<<NSUPER, 256, 0, stream>>>(Fr, Fi, par, Lr, Li, Tr, Ti);
    scanB2_kernel <<<1,      256, 0, stream>>>(Tr, Ti, par, Er, Ei);
    scanC_kernel  <<<NCHUNK, 256, 0, stream>>>(Bu, par, Lr, Li, Er, Ei, Ubf);
    gemm_bt_kernel<true><<<1024, 256, 0, stream>>>(Ubf, Ctm, d_out, Dv, u);
}

// Round 5
// 105.206 us; speedup vs baseline: 2.0408x; 1.0328x over previous
//
#include <hip/hip_runtime.h>
#include <cstdint>
#include <cstddef>

typedef __bf16 bf16x8 __attribute__((ext_vector_type(8)));
typedef float f32x4 __attribute__((ext_vector_type(4)));

#define L_SEQ 32768
#define H_DIM 512
#define P_DIM 256
#define NP2   512      // 2P = K and N of both GEMMs
#define CHUNK 32
#define NCHUNK 1024    // L / CHUNK
#define NSUPER 32      // NCHUNK / 32

__device__ __forceinline__ void gload_lds16(const void* g, void* l) {
    __builtin_amdgcn_global_load_lds(
        (const __attribute__((address_space(1))) void*)g,
        (__attribute__((address_space(3))) void*)l,
        16, 0, 0);
}

// ---------------- per-channel parameter precompute ----------------
// par layout (floats): [0]=Ar [256]=Ai [512]=coefR [768]=coefI
//                      [1024]=PowR (Lbar^32) [1280]=PowI
//                      [1536]=ldr (Re(Lambda)*step) [1792]=ldi (Im(Lambda)*step)
__global__ void prep_kernel(const float* __restrict__ Lre, const float* __restrict__ Lim,
                            const float* __restrict__ lstep, float* __restrict__ par) {
    int p = threadIdx.x;
    if (p >= P_DIM) return;
    float lr = fminf(Lre[p], -1e-4f);       // clip_eigs
    float li = Lim[p];
    float st = expf(lstep[p]);
    float ldr = lr * st;
    float ldi = li * st;
    float er = expf(ldr);
    float ar = er * cosf(ldi);
    float ai = er * sinf(ldi);
    // coeff = (Lambda_bar - 1) / Lambda
    float den = lr * lr + li * li;
    float mr = ar - 1.0f, mi = ai;
    float cr = (mr * lr + mi * li) / den;
    float ci = (mi * lr - mr * li) / den;
    // Lambda_bar^CHUNK = exp(CHUNK * Lambda * step)
    float e32  = expf((float)CHUNK * ldr);
    float ph32 = (float)CHUNK * ldi;
    float pr = e32 * cosf(ph32);
    float pi = e32 * sinf(ph32);
    par[p] = ar;        par[256 + p] = ai;
    par[512 + p] = cr;  par[768 + p] = ci;
    par[1024 + p] = pr; par[1280 + p] = pi;
    par[1536 + p] = ldr; par[1792 + p] = ldi;
}

// Bt[n][k]: n in [0,512) (re rows 0..255, im rows 256..511), k = h in [0,512)
__global__ void build_B_kernel(const float* __restrict__ Bre, const float* __restrict__ Bim,
                               const float* __restrict__ par, __bf16* __restrict__ Bt) {
    int idx = blockIdx.x * blockDim.x + threadIdx.x;   // [0, P*H)
    int p = idx >> 9;
    int h = idx & 511;
    float cr = par[512 + p], ci = par[768 + p];
    float br = Bre[idx], bi = Bim[idx];
    Bt[(size_t)p * NP2 + h]         = (__bf16)(cr * br - ci * bi);
    Bt[(size_t)(256 + p) * NP2 + h] = (__bf16)(cr * bi + ci * br);
}

// Ct[h][q]: q<256 -> 2*C_re[h][q], q>=256 -> -2*C_im[h][q-256]
__global__ void build_C_kernel(const float* __restrict__ Cre, const float* __restrict__ Cim,
                               __bf16* __restrict__ Ct) {
    int idx = blockIdx.x * blockDim.x + threadIdx.x;   // [0, H*P)
    int h = idx >> 8;
    int q = idx & 255;
    Ct[(size_t)h * NP2 + q]       = (__bf16)( 2.0f * Cre[idx]);
    Ct[(size_t)h * NP2 + 256 + q] = (__bf16)(-2.0f * Cim[idx]);
}

// ---------------- GEMM: A(M,512) x Bt(512,512) bf16 (N,K), 128x128 tile, BK=64 ----------------
// 2-phase pipeline: LDS dbuf, counted vmcnt, raw s_barrier, T2 source-side XOR swizzle,
// bijective XCD swizzle, T5 setprio.
// MODE 0 (GEMM1): A is f32 (u), reg-staged (load f32 -> cvt bf16 -> ds_write); out bf16 Bu.
// MODE 1 (GEMM2): A is bf16 (xs), gload_lds-staged; out f32 d_out + D*U (f32 u).
template<int MODE>
__global__ __launch_bounds__(256)
void gemm_bt_kernel(const void* __restrict__ Av, const __bf16* __restrict__ Bt,
                    void* __restrict__ CoutV, const float* __restrict__ Dvec,
                    const float* __restrict__ U) {
    const int K = NP2, N = NP2;
    __shared__ __align__(16) __bf16 As[2][128 * 64];
    __shared__ __align__(16) __bf16 Bs[2][128 * 64];
    const int t = threadIdx.x;
    const int l = t & 63;
    const int w = t >> 6;
    const int wr = w >> 1, wc = w & 1;
    // XCD-aware bijective remap: 1024 blocks = 8 XCDs * 128 slots
    const int b    = blockIdx.x;
    const int n_sw = (b & 7) * 128 + (b >> 3);
    const int row0 = (n_sw >> 2) * 128;
    const int col0 = (n_sw & 3) * 128;
    const int lr = l & 15;
    const int lk = (l >> 4) * 8;
    f32x4 acc[4][4] = {};
    float4 fa[8];   // MODE 0: in-flight A registers (2 float4 per 16B bf16 chunk)

    // B tile: 4 gload_lds16 per thread, source col pre-swizzled (rule #21)
    auto STAGE_B = [&](int buf, int k0) {
#pragma unroll
        for (int i = 0; i < 4; ++i) {
            int off = i * 256 + t;
            int r  = off >> 3;
            int ce = ((off & 7) ^ (r & 7)) * 8;
            gload_lds16(Bt + (size_t)(col0 + r) * K + (k0 + ce), &Bs[buf][off * 8]);
        }
    };
    // MODE 1 A tile: 4 gload_lds16 from bf16 source
    auto STAGE_A_BF16 = [&](int buf, int k0) {
#pragma unroll
        for (int i = 0; i < 4; ++i) {
            int off = i * 256 + t;
            int r  = off >> 3;
            int ce = ((off & 7) ^ (r & 7)) * 8;
            gload_lds16((const __bf16*)Av + (size_t)(row0 + r) * K + (k0 + ce), &As[buf][off * 8]);
        }
    };
    // MODE 0 A tile, part 1: issue 8 dwordx4 loads from f32 source
    auto ISSUE_A_F32 = [&](int k0) {
#pragma unroll
        for (int i = 0; i < 4; ++i) {
            int off = i * 256 + t;
            int r  = off >> 3;
            int cs = ((off & 7) ^ (r & 7)) * 8;
            const float* src = (const float*)Av + (size_t)(row0 + r) * K + (k0 + cs);
            fa[2 * i]     = *reinterpret_cast<const float4*>(src);
            fa[2 * i + 1] = *reinterpret_cast<const float4*>(src + 4);
        }
    };
    // MODE 0 A tile, part 2: cvt + ds_write_b128
    auto WRITE_A = [&](int buf) {
#pragma unroll
        for (int i = 0; i < 4; ++i) {
            int off = i * 256 + t;
            bf16x8 v;
            v[0] = (__bf16)fa[2*i].x;   v[1] = (__bf16)fa[2*i].y;
            v[2] = (__bf16)fa[2*i].z;   v[3] = (__bf16)fa[2*i].w;
            v[4] = (__bf16)fa[2*i+1].x; v[5] = (__bf16)fa[2*i+1].y;
            v[6] = (__bf16)fa[2*i+1].z; v[7] = (__bf16)fa[2*i+1].w;
            *reinterpret_cast<bf16x8*>(&As[buf][off * 8]) = v;
        }
    };

    auto COMPUTE = [&](int buf) {
#pragma unroll
        for (int kk = 0; kk < 64; kk += 32) {
            bf16x8 a[4], b2[4];
            const int ls = (kk + lk) >> 3;
#pragma unroll
            for (int m = 0; m < 4; ++m) {
                int row = wr * 64 + m * 16 + lr;
                a[m] = *reinterpret_cast<const bf16x8*>(&As[buf][row * 64 + ((ls ^ (row & 7)) << 3)]);
            }
#pragma unroll
            for (int n = 0; n < 4; ++n) {
                int row = wc * 64 + n * 16 + lr;
                b2[n] = *reinterpret_cast<const bf16x8*>(&Bs[buf][row * 64 + ((ls ^ (row & 7)) << 3)]);
            }
            __builtin_amdgcn_s_setprio(1);
#pragma unroll
            for (int m = 0; m < 4; ++m)
#pragma unroll
                for (int n = 0; n < 4; ++n)
                    acc[m][n] = __builtin_amdgcn_mfma_f32_16x16x32_bf16(a[m], b2[n], acc[m][n], 0, 0, 0);
            __builtin_amdgcn_s_setprio(0);
        }
    };

    // ---- prologue: stage tile 0 ----
    if constexpr (MODE == 0) {
        ISSUE_A_F32(0);
        STAGE_B(0, 0);
        asm volatile("s_waitcnt vmcnt(4)" ::: "memory");   // 8 A-loads done, 4 B in flight
        WRITE_A(0);
        asm volatile("s_waitcnt lgkmcnt(0)" ::: "memory");
    } else {
        STAGE_A_BF16(0, 0);
        STAGE_B(0, 0);
    }
    int cur = 0;
#pragma unroll
    for (int k0 = 64; k0 < K; k0 += 64) {       // 7 iterations
        if constexpr (MODE == 0) {
            ISSUE_A_F32(k0);
            STAGE_B(cur ^ 1, k0);
            asm volatile("s_waitcnt vmcnt(12)" ::: "memory");  // prev tile's 4 B-lds done
        } else {
            STAGE_A_BF16(cur ^ 1, k0);
            STAGE_B(cur ^ 1, k0);
            asm volatile("s_waitcnt vmcnt(8)" ::: "memory");   // prev tile's 8 lds-loads done
        }
        __builtin_amdgcn_s_barrier();
        __builtin_amdgcn_sched_barrier(0);
        COMPUTE(cur);
        __builtin_amdgcn_sched_barrier(0);
        if constexpr (MODE == 0) {
            asm volatile("s_waitcnt vmcnt(4)" ::: "memory");   // A regs arrived, B stays in flight
            WRITE_A(cur ^ 1);
            asm volatile("s_waitcnt lgkmcnt(0)" ::: "memory");
        }
        __builtin_amdgcn_s_barrier();           // all waves done reading buf[cur]; A(t+1) visible
        __builtin_amdgcn_sched_barrier(0);
        cur ^= 1;
    }
    asm volatile("s_waitcnt vmcnt(0)" ::: "memory");
    __builtin_amdgcn_s_barrier();
    __builtin_amdgcn_sched_barrier(0);
    COMPUTE(cur);

    const int lg = (l >> 4) * 4;
#pragma unroll
    for (int m = 0; m < 4; ++m) {
#pragma unroll
        for (int n = 0; n < 4; ++n) {
            int col = col0 + wc * 64 + n * 16 + lr;
#pragma unroll
            for (int j = 0; j < 4; ++j) {
                int row = row0 + wr * 64 + m * 16 + lg + j;
                size_t o = (size_t)row * N + col;
                if (MODE == 1) {
                    ((float*)CoutV)[o] = acc[m][n][j] + Dvec[col] * U[o];
                } else {
                    ((__bf16*)CoutV)[o] = (__bf16)acc[m][n][j];
                }
            }
        }
    }
}

// ---------------- chunked scan (Bu is bf16) ----------------
// Level 0: per-chunk (32 steps) totals F[g], g in [0,1024)
__global__ void scanA_kernel(const __bf16* __restrict__ Bu, const float* __restrict__ par,
                             float* __restrict__ Fr, float* __restrict__ Fi) {
    int g = blockIdx.x;
    int p = threadIdx.x;
    float ar = par[p], ai = par[256 + p];
    const __bf16* bu = Bu + (size_t)g * CHUNK * NP2;
    float xr = 0.f, xi = 0.f;
#pragma unroll 4
    for (int i = 0; i < CHUNK; ++i) {
        float br = (float)bu[i * NP2 + p];
        float bi = (float)bu[i * NP2 + 256 + p];
        float nr = fmaf(ar, xr, fmaf(-ai, xi, br));
        float ni = fmaf(ar, xi, fmaf( ai, xr, bi));
        xr = nr; xi = ni;
    }
    Fr[g * 256 + p] = xr;
    Fi[g * 256 + p] = xi;
}

// Level 1: 32 blocks; block s scans its 32 chunks. Writes within-super exclusive
// prefixes l[g] and super-chunk totals T[s].
__global__ void scanB1_kernel(const float* __restrict__ Fr, const float* __restrict__ Fi,
                              const float* __restrict__ par,
                              float* __restrict__ Lr, float* __restrict__ Li,
                              float* __restrict__ Tr, float* __restrict__ Ti) {
    int s = blockIdx.x;
    int p = threadIdx.x;
    float pr = par[1024 + p], pi = par[1280 + p];   // Lbar^32
    float er = 0.f, ei = 0.f;
    int base = s * 32;
#pragma unroll
    for (int j = 0; j < 32; ++j) {
        int g = base + j;
        Lr[g * 256 + p] = er;
        Li[g * 256 + p] = ei;
        float fr = Fr[g * 256 + p], fi = Fi[g * 256 + p];
        float nr = fmaf(pr, er, fmaf(-pi, ei, fr));
        float ni = fmaf(pr, ei, fmaf( pi, er, fi));
        er = nr; ei = ni;
    }
    Tr[s * 256 + p] = er;
    Ti[s * 256 + p] = ei;
}

// Level 2: 1 block, serial exclusive scan over 32 super-chunk totals with Lbar^1024.
__global__ void scanB2_kernel(const float* __restrict__ Tr, const float* __restrict__ Ti,
                              const float* __restrict__ par,
                              float* __restrict__ Er, float* __restrict__ Ei) {
    int p = threadIdx.x;
    float ldr = par[1536 + p], ldi = par[1792 + p];
    float e  = expf(1024.0f * ldr);
    float ph = 1024.0f * ldi;
    float qr = e * cosf(ph), qi = e * sinf(ph);     // Lbar^1024
    float er = 0.f, ei = 0.f;
#pragma unroll
    for (int s = 0; s < NSUPER; ++s) {
        Er[s * 256 + p] = er;
        Ei[s * 256 + p] = ei;
        float fr = Tr[s * 256 + p], fi = Ti[s * 256 + p];
        float nr = fmaf(qr, er, fmaf(-qi, ei, fr));
        float ni = fmaf(qr, ei, fmaf( qi, er, fi));
        er = nr; ei = ni;
    }
}

// Final: per-chunk replay with carry = Lbar^(32k) * E[s] + l[g]; writes xs (bf16).
__global__ void scanC_kernel(const __bf16* __restrict__ Bu, const float* __restrict__ par,
                             const float* __restrict__ Lr, const float* __restrict__ Li,
                             const float* __restrict__ Er, const float* __restrict__ Ei,
                             __bf16* __restrict__ xs) {
    int g = blockIdx.x;
    int p = threadIdx.x;
    int s = g >> 5, k = g & 31;
    float ar = par[p], ai = par[256 + p];
    float ldr = par[1536 + p], ldi = par[1792 + p];
    float kk = (float)(32 * k);
    float e  = expf(kk * ldr);
    float ph = kk * ldi;
    float qr = e * cosf(ph), qi = e * sinf(ph);     // Lbar^(32k)
    float er = Er[s * 256 + p], ei = Ei[s * 256 + p];
    float lr0 = Lr[g * 256 + p], li0 = Li[g * 256 + p];
    float xr = fmaf(qr, er, fmaf(-qi, ei, lr0));
    float xi = fmaf(qr, ei, fmaf( qi, er, li0));
    const __bf16* bu = Bu + (size_t)g * CHUNK * NP2;
    __bf16* xo = xs + (size_t)g * CHUNK * NP2;
#pragma unroll 4
    for (int i = 0; i < CHUNK; ++i) {
        float br = (float)bu[i * NP2 + p];
        float bi = (float)bu[i * NP2 + 256 + p];
        float nr = fmaf(ar, xr, fmaf(-ai, xi, br));
        float ni = fmaf(ar, xi, fmaf( ai, xr, bi));
        xr = nr; xi = ni;
        xo[i * NP2 + p]       = (__bf16)xr;
        xo[i * NP2 + 256 + p] = (__bf16)xi;
    }
}

extern "C" void kernel_launch(void* const* d_in, const int* in_sizes, int n_in,
                              void* d_out, int out_size, void* d_ws, size_t ws_size,
                              hipStream_t stream) {
    const float* u   = (const float*)d_in[0];
    const float* Lre = (const float*)d_in[1];
    const float* Lim = (const float*)d_in[2];
    const float* Bre = (const float*)d_in[3];
    const float* Bim = (const float*)d_in[4];
    const float* Cre = (const float*)d_in[5];
    const float* Cim = (const float*)d_in[6];
    const float* Dv  = (const float*)d_in[7];
    const float* lst = (const float*)d_in[8];

    char* w = (char*)d_ws;
    size_t off = 0;
    float* par = (float*)(w + off);      off += 16 * 1024;
    __bf16* Btm = (__bf16*)(w + off);    off += (size_t)NP2 * NP2 * 2;      // 512 KB
    __bf16* Ctm = (__bf16*)(w + off);    off += (size_t)NP2 * NP2 * 2;      // 512 KB
    float* Fr  = (float*)(w + off);      off += (size_t)NCHUNK * 256 * 4;   // 1 MB
    float* Fi  = (float*)(w + off);      off += (size_t)NCHUNK * 256 * 4;
    float* Lr  = (float*)(w + off);      off += (size_t)NCHUNK * 256 * 4;
    float* Li  = (float*)(w + off);      off += (size_t)NCHUNK * 256 * 4;
    float* Tr  = (float*)(w + off);      off += (size_t)NSUPER * 256 * 4;   // 32 KB
    float* Ti  = (float*)(w + off);      off += (size_t)NSUPER * 256 * 4;
    float* Er  = (float*)(w + off);      off += (size_t)NSUPER * 256 * 4;
    float* Ei  = (float*)(w + off);      off += (size_t)NSUPER * 256 * 4;
    __bf16* Xs = (__bf16*)(w + off);     off += (size_t)L_SEQ * NP2 * 2;    // 32 MB (xs)
    if (ws_size < off) return;  // fail loudly (output stays poisoned)

    // Bu: bf16 L x 2P (32 MB) in the lower half of d_out; GEMM2 overwrites
    // all of d_out (f32 output) afterwards.
    __bf16* Bu = (__bf16*)d_out;

    prep_kernel   <<<1,    256, 0, stream>>>(Lre, Lim, lst, par);
    build_B_kernel<<<512,  256, 0, stream>>>(Bre, Bim, par, Btm);
    build_C_kernel<<<512,  256, 0, stream>>>(Cre, Cim, Ctm);
    gemm_bt_kernel<0><<<1024, 256, 0, stream>>>(u, Btm, (void*)Bu, nullptr, nullptr);
    scanA_kernel  <<<NCHUNK, 256, 0, stream>>>(Bu, par, Fr, Fi);
    scanB1_kernel <<<NSUPER, 256, 0, stream>>>(Fr, Fi, par, Lr, Li, Tr, Ti);
    scanB2_kernel <<<1,      256, 0, stream>>>(Tr, Ti, par, Er, Ei);
    scanC_kernel  <<<NCHUNK, 256, 0, stream>>>(Bu, par, Lr, Li, Er, Ei, Xs);
    gemm_bt_kernel<1><<<1024, 256, 0, stream>>>(Xs, Ctm, d_out, Dv, u);
}

// Round 6
// 104.130 us; speedup vs baseline: 2.0619x; 1.0103x over previous
//
#include <hip/hip_runtime.h>
#include <cstdint>
#include <cstddef>

typedef __bf16 bf16x8 __attribute__((ext_vector_type(8)));
typedef float f32x4 __attribute__((ext_vector_type(4)));

#define L_SEQ 32768
#define H_DIM 512
#define P_DIM 256
#define NP2   512      // 2P = K and N of both GEMMs
#define CHUNK 32
#define NCHUNK 1024    // L / CHUNK
#define NSUPER 32      // NCHUNK / 32

__device__ __forceinline__ void gload_lds16(const void* g, void* l) {
    __builtin_amdgcn_global_load_lds(
        (const __attribute__((address_space(1))) void*)g,
        (__attribute__((address_space(3))) void*)l,
        16, 0, 0);
}

// ---------------- per-channel parameter precompute ----------------
// par layout (floats): [0]=Ar [256]=Ai [512]=coefR [768]=coefI
//                      [1024]=PowR (Lbar^32) [1280]=PowI
//                      [1536]=ldr (Re(Lambda)*step) [1792]=ldi (Im(Lambda)*step)
__global__ void prep_kernel(const float* __restrict__ Lre, const float* __restrict__ Lim,
                            const float* __restrict__ lstep, float* __restrict__ par) {
    int p = threadIdx.x;
    if (p >= P_DIM) return;
    float lr = fminf(Lre[p], -1e-4f);       // clip_eigs
    float li = Lim[p];
    float st = expf(lstep[p]);
    float ldr = lr * st;
    float ldi = li * st;
    float er = expf(ldr);
    float ar = er * cosf(ldi);
    float ai = er * sinf(ldi);
    // coeff = (Lambda_bar - 1) / Lambda
    float den = lr * lr + li * li;
    float mr = ar - 1.0f, mi = ai;
    float cr = (mr * lr + mi * li) / den;
    float ci = (mi * lr - mr * li) / den;
    // Lambda_bar^CHUNK = exp(CHUNK * Lambda * step)
    float e32  = expf((float)CHUNK * ldr);
    float ph32 = (float)CHUNK * ldi;
    float pr = e32 * cosf(ph32);
    float pi = e32 * sinf(ph32);
    par[p] = ar;        par[256 + p] = ai;
    par[512 + p] = cr;  par[768 + p] = ci;
    par[1024 + p] = pr; par[1280 + p] = pi;
    par[1536 + p] = ldr; par[1792 + p] = ldi;
}

// Bt[n][k]: n in [0,512) (re rows 0..255, im rows 256..511), k = h in [0,512)
__global__ void build_B_kernel(const float* __restrict__ Bre, const float* __restrict__ Bim,
                               const float* __restrict__ par, __bf16* __restrict__ Bt) {
    int idx = blockIdx.x * blockDim.x + threadIdx.x;   // [0, P*H)
    int p = idx >> 9;
    int h = idx & 511;
    float cr = par[512 + p], ci = par[768 + p];
    float br = Bre[idx], bi = Bim[idx];
    Bt[(size_t)p * NP2 + h]         = (__bf16)(cr * br - ci * bi);
    Bt[(size_t)(256 + p) * NP2 + h] = (__bf16)(cr * bi + ci * br);
}

// Ct[h][q]: q<256 -> 2*C_re[h][q], q>=256 -> -2*C_im[h][q-256]
__global__ void build_C_kernel(const float* __restrict__ Cre, const float* __restrict__ Cim,
                               __bf16* __restrict__ Ct) {
    int idx = blockIdx.x * blockDim.x + threadIdx.x;   // [0, H*P)
    int h = idx >> 8;
    int q = idx & 255;
    Ct[(size_t)h * NP2 + q]       = (__bf16)( 2.0f * Cre[idx]);
    Ct[(size_t)h * NP2 + 256 + q] = (__bf16)(-2.0f * Cim[idx]);
}

__global__ void cast_u_kernel(const float4* __restrict__ in, bf16x8* __restrict__ out, int n8) {
    int i = blockIdx.x * blockDim.x + threadIdx.x;
    if (i >= n8) return;
    float4 a = in[2 * i], b = in[2 * i + 1];
    bf16x8 v;
    v[0] = (__bf16)a.x; v[1] = (__bf16)a.y; v[2] = (__bf16)a.z; v[3] = (__bf16)a.w;
    v[4] = (__bf16)b.x; v[5] = (__bf16)b.y; v[6] = (__bf16)b.z; v[7] = (__bf16)b.w;
    out[i] = v;
}

// ---------------- GEMM: A(M,512) bf16 x Bt(512,512) bf16 (N,K), 128x128 tile, BK=64 ----------------
// A: double-buffered LDS (gload_lds, 1 tile ahead). B: SINGLE-buffered LDS
// (same 512KB matrix for all blocks -> L2-resident; issued and drained same iter).
// LDS = 2*16KB (A) + 16KB (B) = 48KB -> 3 blocks/CU.
// T2 source-side XOR swizzle (rule #21), bijective XCD remap, T5 setprio.
// vmcnt: order per iter = [A(t) old, B(t), A(t+1)] -> vmcnt(4) drains A(t)+B(t).
// FUSE=false: out bf16 (Bu). FUSE=true: out f32 = acc + D[col]*Ubf[o].
template<bool FUSE>
__global__ __launch_bounds__(256)
void gemm_bt_kernel(const __bf16* __restrict__ A, const __bf16* __restrict__ Bt,
                    void* __restrict__ CoutV, const float* __restrict__ Dvec,
                    const __bf16* __restrict__ Ubf) {
    const int K = NP2, N = NP2;
    __shared__ __align__(16) __bf16 As[2][128 * 64];
    __shared__ __align__(16) __bf16 Bs[128 * 64];
    const int t = threadIdx.x;
    const int l = t & 63;
    const int w = t >> 6;
    const int wr = w >> 1, wc = w & 1;
    // XCD-aware bijective remap: 1024 blocks = 8 XCDs * 128 slots
    const int b    = blockIdx.x;
    const int n_sw = (b & 7) * 128 + (b >> 3);
    const int row0 = (n_sw >> 2) * 128;
    const int col0 = (n_sw & 3) * 128;
    const int lr = l & 15;
    const int lk = (l >> 4) * 8;
    f32x4 acc[4][4] = {};

    auto STAGE_A = [&](int buf, int k0) {
#pragma unroll
        for (int i = 0; i < 4; ++i) {
            int off = i * 256 + t;
            int r  = off >> 3;
            int ce = ((off & 7) ^ (r & 7)) * 8;
            gload_lds16(A + (size_t)(row0 + r) * K + (k0 + ce), &As[buf][off * 8]);
        }
    };
    auto STAGE_B = [&](int k0) {
#pragma unroll
        for (int i = 0; i < 4; ++i) {
            int off = i * 256 + t;
            int r  = off >> 3;
            int ce = ((off & 7) ^ (r & 7)) * 8;
            gload_lds16(Bt + (size_t)(col0 + r) * K + (k0 + ce), &Bs[off * 8]);
        }
    };

    auto COMPUTE = [&](int buf) {
#pragma unroll
        for (int kk = 0; kk < 64; kk += 32) {
            bf16x8 a[4], b2[4];
            const int ls = (kk + lk) >> 3;
#pragma unroll
            for (int m = 0; m < 4; ++m) {
                int row = wr * 64 + m * 16 + lr;
                a[m] = *reinterpret_cast<const bf16x8*>(&As[buf][row * 64 + ((ls ^ (row & 7)) << 3)]);
            }
#pragma unroll
            for (int n = 0; n < 4; ++n) {
                int row = wc * 64 + n * 16 + lr;
                b2[n] = *reinterpret_cast<const bf16x8*>(&Bs[row * 64 + ((ls ^ (row & 7)) << 3)]);
            }
            __builtin_amdgcn_s_setprio(1);
#pragma unroll
            for (int m = 0; m < 4; ++m)
#pragma unroll
                for (int n = 0; n < 4; ++n)
                    acc[m][n] = __builtin_amdgcn_mfma_f32_16x16x32_bf16(a[m], b2[n], acc[m][n], 0, 0, 0);
            __builtin_amdgcn_s_setprio(0);
        }
    };

    STAGE_A(0, 0);
    int cur = 0;
#pragma unroll
    for (int k0 = 0; k0 < K; k0 += 64) {        // 8 iterations
        STAGE_B(k0);                            // this tile's B (single buffer)
        if (k0 + 64 < K) {
            STAGE_A(cur ^ 1, k0 + 64);          // next tile's A (double buffer)
            asm volatile("s_waitcnt vmcnt(4)" ::: "memory");  // A(t)+B(t) done, A(t+1) in flight
        } else {
            asm volatile("s_waitcnt vmcnt(0)" ::: "memory");
        }
        __builtin_amdgcn_s_barrier();
        __builtin_amdgcn_sched_barrier(0);
        COMPUTE(cur);
        __builtin_amdgcn_sched_barrier(0);
        __builtin_amdgcn_s_barrier();           // all waves done reading As[cur], Bs
        cur ^= 1;
    }

    const int lg = (l >> 4) * 4;
#pragma unroll
    for (int m = 0; m < 4; ++m) {
#pragma unroll
        for (int n = 0; n < 4; ++n) {
            int col = col0 + wc * 64 + n * 16 + lr;
#pragma unroll
            for (int j = 0; j < 4; ++j) {
                int row = row0 + wr * 64 + m * 16 + lg + j;
                size_t o = (size_t)row * N + col;
                if (FUSE) {
                    ((float*)CoutV)[o] = acc[m][n][j] + Dvec[col] * (float)Ubf[o];
                } else {
                    ((__bf16*)CoutV)[o] = (__bf16)acc[m][n][j];
                }
            }
        }
    }
}

// ---------------- chunked scan (Bu is bf16) ----------------
// Level 0: per-chunk (32 steps) totals F[g], g in [0,1024)
__global__ void scanA_kernel(const __bf16* __restrict__ Bu, const float* __restrict__ par,
                             float* __restrict__ Fr, float* __restrict__ Fi) {
    int g = blockIdx.x;
    int p = threadIdx.x;
    float ar = par[p], ai = par[256 + p];
    const __bf16* bu = Bu + (size_t)g * CHUNK * NP2;
    float xr = 0.f, xi = 0.f;
#pragma unroll 4
    for (int i = 0; i < CHUNK; ++i) {
        float br = (float)bu[i * NP2 + p];
        float bi = (float)bu[i * NP2 + 256 + p];
        float nr = fmaf(ar, xr, fmaf(-ai, xi, br));
        float ni = fmaf(ar, xi, fmaf( ai, xr, bi));
        xr = nr; xi = ni;
    }
    Fr[g * 256 + p] = xr;
    Fi[g * 256 + p] = xi;
}

// Level 1: 32 blocks; block s scans its 32 chunks. Writes within-super exclusive
// prefixes l[g] and super-chunk totals T[s].
__global__ void scanB1_kernel(const float* __restrict__ Fr, const float* __restrict__ Fi,
                              const float* __restrict__ par,
                              float* __restrict__ Lr, float* __restrict__ Li,
                              float* __restrict__ Tr, float* __restrict__ Ti) {
    int s = blockIdx.x;
    int p = threadIdx.x;
    float pr = par[1024 + p], pi = par[1280 + p];   // Lbar^32
    float er = 0.f, ei = 0.f;
    int base = s * 32;
#pragma unroll
    for (int j = 0; j < 32; ++j) {
        int g = base + j;
        Lr[g * 256 + p] = er;
        Li[g * 256 + p] = ei;
        float fr = Fr[g * 256 + p], fi = Fi[g * 256 + p];
        float nr = fmaf(pr, er, fmaf(-pi, ei, fr));
        float ni = fmaf(pr, ei, fmaf( pi, er, fi));
        er = nr; ei = ni;
    }
    Tr[s * 256 + p] = er;
    Ti[s * 256 + p] = ei;
}

// Level 2: 1 block, serial exclusive scan over 32 super-chunk totals with Lbar^1024.
__global__ void scanB2_kernel(const float* __restrict__ Tr, const float* __restrict__ Ti,
                              const float* __restrict__ par,
                              float* __restrict__ Er, float* __restrict__ Ei) {
    int p = threadIdx.x;
    float ldr = par[1536 + p], ldi = par[1792 + p];
    float e  = expf(1024.0f * ldr);
    float ph = 1024.0f * ldi;
    float qr = e * cosf(ph), qi = e * sinf(ph);     // Lbar^1024
    float er = 0.f, ei = 0.f;
#pragma unroll
    for (int s = 0; s < NSUPER; ++s) {
        Er[s * 256 + p] = er;
        Ei[s * 256 + p] = ei;
        float fr = Tr[s * 256 + p], fi = Ti[s * 256 + p];
        float nr = fmaf(qr, er, fmaf(-qi, ei, fr));
        float ni = fmaf(qr, ei, fmaf( qi, er, fi));
        er = nr; ei = ni;
    }
}

// Final: per-chunk replay with carry = Lbar^(32k) * E[s] + l[g]; writes xs (bf16).
__global__ void scanC_kernel(const __bf16* __restrict__ Bu, const float* __restrict__ par,
                             const float* __restrict__ Lr, const float* __restrict__ Li,
                             const float* __restrict__ Er, const float* __restrict__ Ei,
                             __bf16* __restrict__ xs) {
    int g = blockIdx.x;
    int p = threadIdx.x;
    int s = g >> 5, k = g & 31;
    float ar = par[p], ai = par[256 + p];
    float ldr = par[1536 + p], ldi = par[1792 + p];
    float kk = (float)(32 * k);
    float e  = expf(kk * ldr);
    float ph = kk * ldi;
    float qr = e * cosf(ph), qi = e * sinf(ph);     // Lbar^(32k)
    float er = Er[s * 256 + p], ei = Ei[s * 256 + p];
    float lr0 = Lr[g * 256 + p], li0 = Li[g * 256 + p];
    float xr = fmaf(qr, er, fmaf(-qi, ei, lr0));
    float xi = fmaf(qr, ei, fmaf( qi, er, li0));
    const __bf16* bu = Bu + (size_t)g * CHUNK * NP2;
    __bf16* xo = xs + (size_t)g * CHUNK * NP2;
#pragma unroll 4
    for (int i = 0; i < CHUNK; ++i) {
        float br = (float)bu[i * NP2 + p];
        float bi = (float)bu[i * NP2 + 256 + p];
        float nr = fmaf(ar, xr, fmaf(-ai, xi, br));
        float ni = fmaf(ar, xi, fmaf( ai, xr, bi));
        xr = nr; xi = ni;
        xo[i * NP2 + p]       = (__bf16)xr;
        xo[i * NP2 + 256 + p] = (__bf16)xi;
    }
}

extern "C" void kernel_launch(void* const* d_in, const int* in_sizes, int n_in,
                              void* d_out, int out_size, void* d_ws, size_t ws_size,
                              hipStream_t stream) {
    const float* u   = (const float*)d_in[0];
    const float* Lre = (const float*)d_in[1];
    const float* Lim = (const float*)d_in[2];
    const float* Bre = (const float*)d_in[3];
    const float* Bim = (const float*)d_in[4];
    const float* Cre = (const float*)d_in[5];
    const float* Cim = (const float*)d_in[6];
    const float* Dv  = (const float*)d_in[7];
    const float* lst = (const float*)d_in[8];

    char* w = (char*)d_ws;
    size_t off = 0;
    float* par = (float*)(w + off);      off += 16 * 1024;
    __bf16* Btm = (__bf16*)(w + off);    off += (size_t)NP2 * NP2 * 2;      // 512 KB
    __bf16* Ctm = (__bf16*)(w + off);    off += (size_t)NP2 * NP2 * 2;      // 512 KB
    float* Fr  = (float*)(w + off);      off += (size_t)NCHUNK * 256 * 4;   // 1 MB
    float* Fi  = (float*)(w + off);      off += (size_t)NCHUNK * 256 * 4;
    float* Lr  = (float*)(w + off);      off += (size_t)NCHUNK * 256 * 4;
    float* Li  = (float*)(w + off);      off += (size_t)NCHUNK * 256 * 4;
    float* Tr  = (float*)(w + off);      off += (size_t)NSUPER * 256 * 4;   // 32 KB
    float* Ti  = (float*)(w + off);      off += (size_t)NSUPER * 256 * 4;
    float* Er  = (float*)(w + off);      off += (size_t)NSUPER * 256 * 4;
    float* Ei  = (float*)(w + off);      off += (size_t)NSUPER * 256 * 4;
    __bf16* Ubf = (__bf16*)(w + off);    off += (size_t)L_SEQ * H_DIM * 2;  // 32 MB (bf16 u)
    __bf16* Xs  = (__bf16*)(w + off);    off += (size_t)L_SEQ * NP2 * 2;    // 32 MB (xs)
    if (ws_size < off) return;  // fail loudly (output stays poisoned)

    // Bu: bf16 L x 2P (32 MB) in the lower half of d_out; GEMM2 overwrites
    // all of d_out (f32 output) afterwards.
    __bf16* Bu = (__bf16*)d_out;

    prep_kernel   <<<1,    256, 0, stream>>>(Lre, Lim, lst, par);
    build_B_kernel<<<512,  256, 0, stream>>>(Bre, Bim, par, Btm);
    build_C_kernel<<<512,  256, 0, stream>>>(Cre, Cim, Ctm);
    cast_u_kernel <<<8192, 256, 0, stream>>>((const float4*)u, (bf16x8*)Ubf, L_SEQ * H_DIM / 8);
    gemm_bt_kernel<false><<<1024, 256, 0, stream>>>(Ubf, Btm, (void*)Bu, nullptr, nullptr);
    scanA_kernel  <<<NCHUNK, 256, 0, stream>>>(Bu, par, Fr, Fi);
    scanB1_kernel <<<NSUPER, 256, 0, stream>>>(Fr, Fi, par, Lr, Li, Tr, Ti);
    scanB2_kernel <<<1,      256, 0, stream>>>(Tr, Ti, par, Er, Ei);
    scanC_kernel  <<<NCHUNK, 256, 0, stream>>>(Bu, par, Lr, Li, Er, Ei, Xs);
    gemm_bt_kernel<true><<<1024, 256, 0, stream>>>(Xs, Ctm, d_out, Dv, Ubf);
}

// Round 8
// 103.408 us; speedup vs baseline: 2.0763x; 1.0070x over previous
//
#include <hip/hip_runtime.h>
#include <cstdint>
#include <cstddef>

typedef __bf16 bf16x8 __attribute__((ext_vector_type(8)));
typedef float f32x4 __attribute__((ext_vector_type(4)));

#define L_SEQ 32768
#define H_DIM 512
#define P_DIM 256
#define NP2   512      // 2P = K and N of both GEMMs
#define CHUNK 32
#define NCHUNK 1024    // L / CHUNK
#define NSUPER 32      // NCHUNK / 32

__device__ __forceinline__ void gload_lds16(const void* g, void* l) {
    __builtin_amdgcn_global_load_lds(
        (const __attribute__((address_space(1))) void*)g,
        (__attribute__((address_space(3))) void*)l,
        16, 0, 0);
}

// ---------------- per-channel parameter precompute ----------------
// par layout (floats): [0]=Ar [256]=Ai [512]=coefR [768]=coefI
//                      [1024]=PowR (Lbar^32) [1280]=PowI
//                      [1536]=ldr (Re(Lambda)*step) [1792]=ldi (Im(Lambda)*step)
__global__ void prep_kernel(const float* __restrict__ Lre, const float* __restrict__ Lim,
                            const float* __restrict__ lstep, float* __restrict__ par) {
    int p = threadIdx.x;
    if (p >= P_DIM) return;
    float lr = fminf(Lre[p], -1e-4f);       // clip_eigs
    float li = Lim[p];
    float st = expf(lstep[p]);
    float ldr = lr * st;
    float ldi = li * st;
    float er = expf(ldr);
    float ar = er * cosf(ldi);
    float ai = er * sinf(ldi);
    // coeff = (Lambda_bar - 1) / Lambda
    float den = lr * lr + li * li;
    float mr = ar - 1.0f, mi = ai;
    float cr = (mr * lr + mi * li) / den;
    float ci = (mi * lr - mr * li) / den;
    // Lambda_bar^CHUNK = exp(CHUNK * Lambda * step)
    float e32  = expf((float)CHUNK * ldr);
    float ph32 = (float)CHUNK * ldi;
    float pr = e32 * cosf(ph32);
    float pi = e32 * sinf(ph32);
    par[p] = ar;        par[256 + p] = ai;
    par[512 + p] = cr;  par[768 + p] = ci;
    par[1024 + p] = pr; par[1280 + p] = pi;
    par[1536 + p] = ldr; par[1792 + p] = ldi;
}

// Merged B/C builders. Blocks [0,512): Bt[n][k] (re rows 0..255, im rows 256..511).
// Blocks [512,1024): Ct[h][q] with 2x / -2x signs folded.
__global__ void build_BC_kernel(const float* __restrict__ Bre, const float* __restrict__ Bim,
                                const float* __restrict__ par,
                                const float* __restrict__ Cre, const float* __restrict__ Cim,
                                __bf16* __restrict__ Bt, __bf16* __restrict__ Ct) {
    int b = blockIdx.x;
    if (b < 512) {
        int idx = b * 256 + threadIdx.x;       // [0, P*H)
        int p = idx >> 9;
        float cr = par[512 + p], ci = par[768 + p];
        float br = Bre[idx], bi = Bim[idx];
        int h = idx & 511;
        Bt[(size_t)p * NP2 + h]         = (__bf16)(cr * br - ci * bi);
        Bt[(size_t)(256 + p) * NP2 + h] = (__bf16)(cr * bi + ci * br);
    } else {
        int idx = (b - 512) * 256 + threadIdx.x;   // [0, H*P)
        int h = idx >> 8;
        int q = idx & 255;
        Ct[(size_t)h * NP2 + q]       = (__bf16)( 2.0f * Cre[idx]);
        Ct[(size_t)h * NP2 + 256 + q] = (__bf16)(-2.0f * Cim[idx]);
    }
}

__global__ void cast_u_kernel(const float4* __restrict__ in, bf16x8* __restrict__ out, int n8) {
    int i = blockIdx.x * blockDim.x + threadIdx.x;
    if (i >= n8) return;
    float4 a = in[2 * i], b = in[2 * i + 1];
    bf16x8 v;
    v[0] = (__bf16)a.x; v[1] = (__bf16)a.y; v[2] = (__bf16)a.z; v[3] = (__bf16)a.w;
    v[4] = (__bf16)b.x; v[5] = (__bf16)b.y; v[6] = (__bf16)b.z; v[7] = (__bf16)b.w;
    out[i] = v;
}

// ---------------- GEMM: A(M,512) bf16 x Bt(512,512) bf16 (N,K), 128x128 tile, BK=64 ----------------
// Deep counted pipeline, FULL-TILE staging units only (gload_lds needs linear
// contiguous dest — R7's column-half scatter violated m104 and NaN'd).
// A: 3 buffers, prefetched 2 tiles ahead (~2 iters > HBM latency).
// B: 2 buffers, 1 tile ahead (B is 512KB, L2-resident).
// LDS = 48+32 = 80KB -> 2 blocks/CU.
// vmcnt ledger (4 loads/unit; per-iter issue order B(t+1) then A(t+2)):
//   steady queue at wait = [A(t),B(t),A(t+1),B(t+1),A(t+2)] = 20 -> vmcnt(12)
//   drains exactly A(t)+B(t). ks=6 -> vmcnt(8); ks=7 -> vmcnt(0).
// Buffer overwrite (A(t+2)->buf[(t-1)%3], B(t+1)->buf[(t-1)&1]) is fenced by the
// trailing barrier of iter t-1. Full 8-slot XOR source-side swizzle (rule #21).
// FUSE=false: out bf16 (Bu). FUSE=true: out f32 = acc + D[col]*Ubf[o].
template<bool FUSE>
__global__ __launch_bounds__(256)
void gemm_bt_kernel(const __bf16* __restrict__ A, const __bf16* __restrict__ Bt,
                    void* __restrict__ CoutV, const float* __restrict__ Dvec,
                    const __bf16* __restrict__ Ubf) {
    const int K = NP2, N = NP2;
    __shared__ __align__(16) __bf16 As[3][128 * 64];
    __shared__ __align__(16) __bf16 Bs[2][128 * 64];
    const int t = threadIdx.x;
    const int l = t & 63;
    const int w = t >> 6;
    const int wr = w >> 1, wc = w & 1;
    // XCD-aware bijective remap: 1024 blocks = 8 XCDs * 128 slots
    const int b    = blockIdx.x;
    const int n_sw = (b & 7) * 128 + (b >> 3);
    const int row0 = (n_sw >> 2) * 128;
    const int col0 = (n_sw & 3) * 128;
    const int lr = l & 15;
    const int lk = (l >> 4) * 8;
    f32x4 acc[4][4] = {};

    // Full tile = 4 gload_lds per thread, contiguous dest (off*16B), swizzled source.
    auto STAGE_A = [&](int buf, int k0) {
#pragma unroll
        for (int i = 0; i < 4; ++i) {
            int off = i * 256 + t;
            int r  = off >> 3;
            int ce = ((off & 7) ^ (r & 7)) * 8;
            gload_lds16(A + (size_t)(row0 + r) * K + (k0 + ce), &As[buf][off * 8]);
        }
    };
    auto STAGE_B = [&](int buf, int k0) {
#pragma unroll
        for (int i = 0; i < 4; ++i) {
            int off = i * 256 + t;
            int r  = off >> 3;
            int ce = ((off & 7) ^ (r & 7)) * 8;
            gload_lds16(Bt + (size_t)(col0 + r) * K + (k0 + ce), &Bs[buf][off * 8]);
        }
    };

    auto COMPUTE = [&](int ba, int bb) {
#pragma unroll
        for (int kk = 0; kk < 64; kk += 32) {
            bf16x8 a[4], b2[4];
            const int ls = (kk + lk) >> 3;
#pragma unroll
            for (int m = 0; m < 4; ++m) {
                int row = wr * 64 + m * 16 + lr;
                a[m] = *reinterpret_cast<const bf16x8*>(&As[ba][row * 64 + ((ls ^ (row & 7)) << 3)]);
            }
#pragma unroll
            for (int n = 0; n < 4; ++n) {
                int row = wc * 64 + n * 16 + lr;
                b2[n] = *reinterpret_cast<const bf16x8*>(&Bs[bb][row * 64 + ((ls ^ (row & 7)) << 3)]);
            }
            __builtin_amdgcn_s_setprio(1);
#pragma unroll
            for (int m = 0; m < 4; ++m)
#pragma unroll
                for (int n = 0; n < 4; ++n)
                    acc[m][n] = __builtin_amdgcn_mfma_f32_16x16x32_bf16(a[m], b2[n], acc[m][n], 0, 0, 0);
            __builtin_amdgcn_s_setprio(0);
        }
    };

    // prologue: A0, B0, A1  (queue = 12)
    STAGE_A(0, 0);
    STAGE_B(0, 0);
    STAGE_A(1, 64);
#pragma unroll
    for (int ks = 0; ks < 8; ++ks) {
        if (ks + 1 < 8) STAGE_B((ks + 1) & 1, (ks + 1) * 64);
        if (ks + 2 < 8) STAGE_A((ks + 2) % 3, (ks + 2) * 64);
        if (ks <= 5)      { asm volatile("s_waitcnt vmcnt(12)" ::: "memory"); }
        else if (ks == 6) { asm volatile("s_waitcnt vmcnt(8)"  ::: "memory"); }
        else              { asm volatile("s_waitcnt vmcnt(0)"  ::: "memory"); }
        __builtin_amdgcn_s_barrier();           // A(ks),B(ks) staged by ALL waves
        __builtin_amdgcn_sched_barrier(0);
        COMPUTE(ks % 3, ks & 1);
        __builtin_amdgcn_sched_barrier(0);
        __builtin_amdgcn_s_barrier();           // all waves done reading bufs of tile ks
    }

    const int lg = (l >> 4) * 4;
#pragma unroll
    for (int m = 0; m < 4; ++m) {
#pragma unroll
        for (int n = 0; n < 4; ++n) {
            int col = col0 + wc * 64 + n * 16 + lr;
#pragma unroll
            for (int j = 0; j < 4; ++j) {
                int row = row0 + wr * 64 + m * 16 + lg + j;
                size_t o = (size_t)row * N + col;
                if (FUSE) {
                    ((float*)CoutV)[o] = acc[m][n][j] + Dvec[col] * (float)Ubf[o];
                } else {
                    ((__bf16*)CoutV)[o] = (__bf16)acc[m][n][j];
                }
            }
        }
    }
}

// ---------------- chunked scan (Bu is bf16) ----------------
// Level 0: per-chunk (32 steps) totals F[g], g in [0,1024)
__global__ void scanA_kernel(const __bf16* __restrict__ Bu, const float* __restrict__ par,
                             float* __restrict__ Fr, float* __restrict__ Fi) {
    int g = blockIdx.x;
    int p = threadIdx.x;
    float ar = par[p], ai = par[256 + p];
    const __bf16* bu = Bu + (size_t)g * CHUNK * NP2;
    float xr = 0.f, xi = 0.f;
#pragma unroll 4
    for (int i = 0; i < CHUNK; ++i) {
        float br = (float)bu[i * NP2 + p];
        float bi = (float)bu[i * NP2 + 256 + p];
        float nr = fmaf(ar, xr, fmaf(-ai, xi, br));
        float ni = fmaf(ar, xi, fmaf( ai, xr, bi));
        xr = nr; xi = ni;
    }
    Fr[g * 256 + p] = xr;
    Fi[g * 256 + p] = xi;
}

// Level 1: 32 blocks; block s scans its 32 chunks. Writes within-super exclusive
// prefixes l[g] and super-chunk totals T[s].
__global__ void scanB1_kernel(const float* __restrict__ Fr, const float* __restrict__ Fi,
                              const float* __restrict__ par,
                              float* __restrict__ Lr, float* __restrict__ Li,
                              float* __restrict__ Tr, float* __restrict__ Ti) {
    int s = blockIdx.x;
    int p = threadIdx.x;
    float pr = par[1024 + p], pi = par[1280 + p];   // Lbar^32
    float er = 0.f, ei = 0.f;
    int base = s * 32;
#pragma unroll
    for (int j = 0; j < 32; ++j) {
        int g = base + j;
        Lr[g * 256 + p] = er;
        Li[g * 256 + p] = ei;
        float fr = Fr[g * 256 + p], fi = Fi[g * 256 + p];
        float nr = fmaf(pr, er, fmaf(-pi, ei, fr));
        float ni = fmaf(pr, ei, fmaf( pi, er, fi));
        er = nr; ei = ni;
    }
    Tr[s * 256 + p] = er;
    Ti[s * 256 + p] = ei;
}

// Level 2: 1 block, serial exclusive scan over 32 super-chunk totals with Lbar^1024.
__global__ void scanB2_kernel(const float* __restrict__ Tr, const float* __restrict__ Ti,
                              const float* __restrict__ par,
                              float* __restrict__ Er, float* __restrict__ Ei) {
    int p = threadIdx.x;
    float ldr = par[1536 + p], ldi = par[1792 + p];
    float e  = expf(1024.0f * ldr);
    float ph = 1024.0f * ldi;
    float qr = e * cosf(ph), qi = e * sinf(ph);     // Lbar^1024
    float er = 0.f, ei = 0.f;
#pragma unroll
    for (int s = 0; s < NSUPER; ++s) {
        Er[s * 256 + p] = er;
        Ei[s * 256 + p] = ei;
        float fr = Tr[s * 256 + p], fi = Ti[s * 256 + p];
        float nr = fmaf(qr, er, fmaf(-qi, ei, fr));
        float ni = fmaf(qr, ei, fmaf( qi, er, fi));
        er = nr; ei = ni;
    }
}

// Final: per-chunk replay with carry = Lbar^(32k) * E[s] + l[g]; writes xs (bf16).
__global__ void scanC_kernel(const __bf16* __restrict__ Bu, const float* __restrict__ par,
                             const float* __restrict__ Lr, const float* __restrict__ Li,
                             const float* __restrict__ Er, const float* __restrict__ Ei,
                             __bf16* __restrict__ xs) {
    int g = blockIdx.x;
    int p = threadIdx.x;
    int s = g >> 5, k = g & 31;
    float ar = par[p], ai = par[256 + p];
    float ldr = par[1536 + p], ldi = par[1792 + p];
    float kk = (float)(32 * k);
    float e  = expf(kk * ldr);
    float ph = kk * ldi;
    float qr = e * cosf(ph), qi = e * sinf(ph);     // Lbar^(32k)
    float er = Er[s * 256 + p], ei = Ei[s * 256 + p];
    float lr0 = Lr[g * 256 + p], li0 = Li[g * 256 + p];
    float xr = fmaf(qr, er, fmaf(-qi, ei, lr0));
    float xi = fmaf(qr, ei, fmaf( qi, er, li0));
    const __bf16* bu = Bu + (size_t)g * CHUNK * NP2;
    __bf16* xo = xs + (size_t)g * CHUNK * NP2;
#pragma unroll 4
    for (int i = 0; i < CHUNK; ++i) {
        float br = (float)bu[i * NP2 + p];
        float bi = (float)bu[i * NP2 + 256 + p];
        float nr = fmaf(ar, xr, fmaf(-ai, xi, br));
        float ni = fmaf(ar, xi, fmaf( ai, xr, bi));
        xr = nr; xi = ni;
        xo[i * NP2 + p]       = (__bf16)xr;
        xo[i * NP2 + 256 + p] = (__bf16)xi;
    }
}

extern "C" void kernel_launch(void* const* d_in, const int* in_sizes, int n_in,
                              void* d_out, int out_size, void* d_ws, size_t ws_size,
                              hipStream_t stream) {
    const float* u   = (const float*)d_in[0];
    const float* Lre = (const float*)d_in[1];
    const float* Lim = (const float*)d_in[2];
    const float* Bre = (const float*)d_in[3];
    const float* Bim = (const float*)d_in[4];
    const float* Cre = (const float*)d_in[5];
    const float* Cim = (const float*)d_in[6];
    const float* Dv  = (const float*)d_in[7];
    const float* lst = (const float*)d_in[8];

    char* w = (char*)d_ws;
    size_t off = 0;
    float* par = (float*)(w + off);      off += 16 * 1024;
    __bf16* Btm = (__bf16*)(w + off);    off += (size_t)NP2 * NP2 * 2;      // 512 KB
    __bf16* Ctm = (__bf16*)(w + off);    off += (size_t)NP2 * NP2 * 2;      // 512 KB
    float* Fr  = (float*)(w + off);      off += (size_t)NCHUNK * 256 * 4;   // 1 MB
    float* Fi  = (float*)(w + off);      off += (size_t)NCHUNK * 256 * 4;
    float* Lr  = (float*)(w + off);      off += (size_t)NCHUNK * 256 * 4;
    float* Li  = (float*)(w + off);      off += (size_t)NCHUNK * 256 * 4;
    float* Tr  = (float*)(w + off);      off += (size_t)NSUPER * 256 * 4;   // 32 KB
    float* Ti  = (float*)(w + off);      off += (size_t)NSUPER * 256 * 4;
    float* Er  = (float*)(w + off);      off += (size_t)NSUPER * 256 * 4;
    float* Ei  = (float*)(w + off);      off += (size_t)NSUPER * 256 * 4;
    __bf16* Ubf = (__bf16*)(w + off);    off += (size_t)L_SEQ * H_DIM * 2;  // 32 MB (bf16 u)
    __bf16* Xs  = (__bf16*)(w + off);    off += (size_t)L_SEQ * NP2 * 2;    // 32 MB (xs)
    if (ws_size < off) return;  // fail loudly (output stays poisoned)

    // Bu: bf16 L x 2P (32 MB) in the lower half of d_out; GEMM2 overwrites
    // all of d_out (f32 output) afterwards.
    __bf16* Bu = (__bf16*)d_out;

    prep_kernel    <<<1,    256, 0, stream>>>(Lre, Lim, lst, par);
    build_BC_kernel<<<1024, 256, 0, stream>>>(Bre, Bim, par, Cre, Cim, Btm, Ctm);
    cast_u_kernel  <<<8192, 256, 0, stream>>>((const float4*)u, (bf16x8*)Ubf, L_SEQ * H_DIM / 8);
    gemm_bt_kernel<false><<<1024, 256, 0, stream>>>(Ubf, Btm, (void*)Bu, nullptr, nullptr);
    scanA_kernel   <<<NCHUNK, 256, 0, stream>>>(Bu, par, Fr, Fi);
    scanB1_kernel  <<<NSUPER, 256, 0, stream>>>(Fr, Fi, par, Lr, Li, Tr, Ti);
    scanB2_kernel  <<<1,      256, 0, stream>>>(Tr, Ti, par, Er, Ei);
    scanC_kernel   <<<NCHUNK, 256, 0, stream>>>(Bu, par, Lr, Li, Er, Ei, Xs);
    gemm_bt_kernel<true><<<1024, 256, 0, stream>>>(Xs, Ctm, d_out, Dv, Ubf);
}